// Round 5
// baseline (642.443 us; speedup 1.0000x reference)
//
#include <hip/hip_runtime.h>
#include <hip/hip_bf16.h>

#define LEAK 0.2f

__device__ __forceinline__ float lrelu(float a) { return a > 0.0f ? a : LEAK * a; }

typedef __attribute__((ext_vector_type(8))) short short8;
typedef __attribute__((ext_vector_type(4))) float f32x4;

// bf16 RNE rounding done manually (no dependence on __hip_bfloat16 ABI).
__device__ __forceinline__ unsigned short bf16_hi_bits(float x) {
    unsigned u = __builtin_bit_cast(unsigned, x);
    unsigned r = u + 0x7fffu + ((u >> 16) & 1u);
    return (unsigned short)(r >> 16);
}
__device__ __forceinline__ float bf16_to_f32(unsigned short h) {
    unsigned u = ((unsigned)h) << 16;
    return __builtin_bit_cast(float, u);
}

// ---------------------------------------------------------------------------
// Implicit-GEMM conv + leaky ReLU (fp32 vector path — conv1/conv2).
// ---------------------------------------------------------------------------
template<int CI, int ST, int KH, int KW, int KIN, int KP,
         int PIH, int PIW, int LP, int OW, int PPI,
         int CO, int NT, int MR, int NR, int OSH, int OSW, int OR0, int OC0,
         int MINW, int NTHR, int BK>
__global__ __launch_bounds__(NTHR, MINW) void conv_gemm_k(
    const float* __restrict__ in,    // padded input [img*CI + ci][PIH][PIW]
    const float* __restrict__ wT,    // [KP][CO]
    const float* __restrict__ bias,
    float* __restrict__ out)
{
    constexpr int KT  = KP / BK;
    constexpr int TXW = NT / 4;         // B staging pixel-quads per k-row
    constexpr int TXN = NT / NR;        // compute columns
    constexpr int BT  = BK * NT / 4;
    constexpr int AT  = BK * CO / 4;
    constexpr int BI  = (BT + NTHR - 1) / NTHR;
    constexpr int AI  = (AT + NTHR - 1) / NTHR;
    constexpr int ASZ = BK * CO;
    constexpr int BSZ = BK * NT;

    __shared__ float sm[2 * ASZ + 2 * BSZ];

    const int tid = threadIdx.x;
    const int bx  = blockIdx.x;
    const int tx  = tid % TXN;
    const int ty  = tid / TXN;

    // ---- per-thread staging geometry (K-independent) ----
    int bofs[BI], bkl[BI], bcol[BI];
#pragma unroll
    for (int q = 0; q < BI; ++q) {
        int task = tid + q * NTHR;
        if ((BT % NTHR == 0) || task < BT) {
            int kl  = task / TXW;
            int pxq = task % TXW;
            int px0 = bx * NT + pxq * 4;
            int img = px0 / PPI;
            int n   = px0 % PPI;
            int oh  = n / OW, ow = n % OW;
            bofs[q] = ((img * CI) * PIH + oh * ST) * PIW + ow * ST + LP;
            bkl[q]  = kl;
            // even/odd group split for NR==8 (conflict-free 8-wide reads)
            bcol[q] = (NR == 8) ? (((pxq & 1) * (TXW / 2) + (pxq >> 1)) * 4)
                                : (pxq * 4);
        }
    }

    float  br[BI][4];
    float4 ar[AI];

    auto gather = [&](int it) {
        int k0 = it * BK;
#pragma unroll
        for (int q = 0; q < BI; ++q) {
            int task = tid + q * NTHR;
            if ((BT % NTHR == 0) || task < BT) {
                int k = k0 + bkl[q];
                if (KP > KIN) k = min(k, KIN - 1);   // padded-K tail (weights 0)
                int ci  = k / (KH * KW);
                int rem = k - ci * (KH * KW);
                int kh  = rem / KW;
                int kw  = rem - kh * KW;
                const float* __restrict__ s = in + bofs[q] + (ci * PIH + kh) * PIW + kw;
                br[q][0] = s[0]; br[q][1] = s[ST]; br[q][2] = s[2 * ST]; br[q][3] = s[3 * ST];
            }
        }
#pragma unroll
        for (int p = 0; p < AI; ++p) {
            int task = tid + p * NTHR;
            if ((AT % NTHR == 0) || task < AT)
                ar[p] = *(const float4*)&wT[(size_t)k0 * CO + task * 4];
        }
    };

    float acc[MR][NR];
#pragma unroll
    for (int j = 0; j < MR; ++j) {
        float bv = bias[ty * MR + j];
#pragma unroll
        for (int i = 0; i < NR; ++i) acc[j][i] = bv;
    }

    gather(0);
    for (int it = 0; it < KT; ++it) {
        const int p = it & 1;
        float* __restrict__ Asb = sm + p * ASZ;
        float* __restrict__ Bsb = sm + 2 * ASZ + p * BSZ;
#pragma unroll
        for (int pa = 0; pa < AI; ++pa) {
            int task = tid + pa * NTHR;
            if ((AT % NTHR == 0) || task < AT)
                *(float4*)&Asb[task * 4] = ar[pa];
        }
#pragma unroll
        for (int q = 0; q < BI; ++q) {
            int task = tid + q * NTHR;
            if ((BT % NTHR == 0) || task < BT)
                *(float4*)&Bsb[bkl[q] * NT + bcol[q]] =
                    make_float4(br[q][0], br[q][1], br[q][2], br[q][3]);
        }
        __syncthreads();
        if (it + 1 < KT) gather(it + 1);
#pragma unroll
        for (int k = 0; k < BK; ++k) {
            float b[NR], a[MR];
            if (NR == 8) {
                // split layout: logical groups {2tx, 2tx+1} at {tx, NT/8+tx}
                *(float4*)&b[0] = *(const float4*)&Bsb[k * NT + tx * 4];
                *(float4*)&b[4] = *(const float4*)&Bsb[k * NT + NT / 2 + tx * 4];
            } else {
#pragma unroll
                for (int i = 0; i < NR / 4; ++i)
                    *(float4*)&b[4 * i] = *(const float4*)&Bsb[k * NT + tx * NR + 4 * i];
            }
#pragma unroll
            for (int j = 0; j < MR / 4; ++j)
                *(float4*)&a[4 * j] = *(const float4*)&Asb[k * CO + ty * MR + 4 * j];
#pragma unroll
            for (int j = 0; j < MR; ++j)
#pragma unroll
                for (int i = 0; i < NR; ++i)
                    acc[j][i] += a[j] * b[i];
        }
    }

    // ---- store (NR consecutive px share one row; OC0/ow 4-aligned) ----
    {
        int pxs = bx * NT + tx * NR;
        int img = pxs / PPI;
        int n   = pxs % PPI;
        int oh  = n / OW, ow = n % OW;
#pragma unroll
        for (int j = 0; j < MR; ++j) {
            int co = ty * MR + j;
            size_t off = (((size_t)img * CO + co) * OSH + (oh + OR0)) * OSW + (ow + OC0);
#pragma unroll
            for (int q = 0; q < NR / 4; ++q) {
                float4 v = make_float4(lrelu(acc[j][4 * q + 0]), lrelu(acc[j][4 * q + 1]),
                                       lrelu(acc[j][4 * q + 2]), lrelu(acc[j][4 * q + 3]));
                *(float4*)&out[off + 4 * q] = v;
            }
        }
    }
}

// ---------------------------------------------------------------------------
// Weight transpose: wT[k][co] = w[co][k], K padded to KP with zeros.
// ---------------------------------------------------------------------------
template<int CO, int KIN, int KP>
__global__ __launch_bounds__(256) void wtr_k(const float* __restrict__ w,
                                             float* __restrict__ wT) {
    int i = blockIdx.x * 256 + threadIdx.x;
    if (i >= KP * CO) return;
    int k = i / CO, co = i % CO;
    wT[i] = (k < KIN) ? w[(size_t)co * KIN + k] : 0.0f;
}

// ---------------------------------------------------------------------------
// Pack fp32 -> dword {bf16 hi (low16), bf16 lo (high16)}. x ~= hi + lo.
// ---------------------------------------------------------------------------
__global__ __launch_bounds__(256) void split_pack_k(const float* __restrict__ src,
                                                    unsigned* __restrict__ dst, int n) {
    for (int i = blockIdx.x * 256 + threadIdx.x; i < n; i += gridDim.x * 256) {
        float x = src[i];
        unsigned short h = bf16_hi_bits(x);
        float lo = x - bf16_to_f32(h);
        unsigned short l = bf16_hi_bits(lo);
        dst[i] = (unsigned)h | ((unsigned)l << 16);
    }
}

// ---------------------------------------------------------------------------
// conv3 as bf16 hi/lo split-GEMM on MFMA (REAL — writes c3).
// out[co][px] = lrelu(bias + sum_k w[k][co]*act[k][px]),
// each product ~ HH + HL + LH in bf16 (missing LL ~ 2^-18 relative).
// Block: 64co x 64px, 4 waves, each wave 32co x 32px = 2x2 16x16 frags.
// BK=32 = one mfma_f32_16x16x32_bf16 K-chunk; double-buffered LDS;
// rows padded to 40 shorts (80B stride) -> <=2-way bank aliasing (free).
// Frag mappings per m89/m91: A[l&15][(l>>4)*8+j], B[(l>>4)*8+j][l&15],
// C/D col=lane&15 (px), row=(lane>>4)*4+reg (co).
// ---------------------------------------------------------------------------
__global__ __launch_bounds__(256, 2) void conv3_mfma_k(
    const unsigned* __restrict__ c2s,   // packed hi/lo of c2p, [img*64+ci][58][64]
    const unsigned* __restrict__ w3s,   // packed hi/lo of wT3, [576][128]
    const float* __restrict__ bias,
    float* __restrict__ outp)           // c3 [32*128][56*56]
{
    __shared__ short8 smq[2560];        // 2 buf x 4 arrays x 64 rows x 40 shorts
    short* const lds = (short*)smq;

    const int tid  = threadIdx.x;
    const int lane = tid & 63;
    const int wv   = tid >> 6;          // wave 0..3
    const int bx   = blockIdx.x;        // 49 px tiles
    const int by   = blockIdx.y;        // 2 co tiles
    const int bz   = blockIdx.z;        // 32 imgs

    // staging role: row = lane, k-slot = wave (8 k's each)
    const int sub = wv;
    const int row = lane;

    const int n  = bx * 64 + row;            // 0..3135
    const int oh = n / 56, ow = n % 56;
    const int bbase = ((bz * 64) * 58 + oh) * 64 + (ow + 3);
    const int coA   = by * 64 + row;

    unsigned Au[8], Bu[8];
    auto gather = [&](int it) {
        int k0 = it * 32 + sub * 8;
#pragma unroll
        for (int j = 0; j < 8; ++j) {
            int k  = k0 + j;
            Au[j]  = w3s[k * 128 + coA];
            int ci = k / 9, r9 = k - ci * 9;
            int kh = r9 / 3, kw = r9 - kh * 3;
            Bu[j]  = c2s[bbase + ci * 3712 + kh * 64 + kw];
        }
    };

    f32x4 acc[2][2] = {};

    const int cw = wv & 1, pw = wv >> 1;
    const int r15 = lane & 15, kg = lane >> 4;

    gather(0);
    for (int it = 0; it < 18; ++it) {
        const int p = it & 1;
        {
            short8 ah, al, bh, bl;
#pragma unroll
            for (int j = 0; j < 8; ++j) {
                ah[j] = (short)(Au[j] & 0xffffu);
                al[j] = (short)(Au[j] >> 16);
                bh[j] = (short)(Bu[j] & 0xffffu);
                bl[j] = (short)(Bu[j] >> 16);
            }
            const int idx = row * 40 + sub * 8;
            *(short8*)&lds[(p * 4 + 0) * 2560 + idx] = ah;
            *(short8*)&lds[(p * 4 + 1) * 2560 + idx] = al;
            *(short8*)&lds[(p * 4 + 2) * 2560 + idx] = bh;
            *(short8*)&lds[(p * 4 + 3) * 2560 + idx] = bl;
        }
        __syncthreads();
        if (it + 1 < 18) gather(it + 1);

        const short* AsH = lds + (p * 4 + 0) * 2560;
        const short* AsL = lds + (p * 4 + 1) * 2560;
        const short* BsH = lds + (p * 4 + 2) * 2560;
        const short* BsL = lds + (p * 4 + 3) * 2560;
        short8 aH[2], aL[2], bH[2], bL[2];
#pragma unroll
        for (int tq = 0; tq < 2; ++tq) {
            const int ra = (cw * 32 + tq * 16 + r15) * 40 + kg * 8;
            aH[tq] = *(const short8*)&AsH[ra];
            aL[tq] = *(const short8*)&AsL[ra];
            const int rb = (pw * 32 + tq * 16 + r15) * 40 + kg * 8;
            bH[tq] = *(const short8*)&BsH[rb];
            bL[tq] = *(const short8*)&BsL[rb];
        }
#pragma unroll
        for (int ct = 0; ct < 2; ++ct)
#pragma unroll
            for (int pt = 0; pt < 2; ++pt) {
                acc[ct][pt] = __builtin_amdgcn_mfma_f32_16x16x32_bf16(aH[ct], bH[pt], acc[ct][pt], 0, 0, 0);
                acc[ct][pt] = __builtin_amdgcn_mfma_f32_16x16x32_bf16(aH[ct], bL[pt], acc[ct][pt], 0, 0, 0);
                acc[ct][pt] = __builtin_amdgcn_mfma_f32_16x16x32_bf16(aL[ct], bH[pt], acc[ct][pt], 0, 0, 0);
            }
    }

    // C/D: col = lane&15 -> px, row = (lane>>4)*4+reg -> co
#pragma unroll
    for (int ct = 0; ct < 2; ++ct)
#pragma unroll
        for (int pt = 0; pt < 2; ++pt)
#pragma unroll
            for (int rg = 0; rg < 4; ++rg) {
                int co = by * 64 + cw * 32 + ct * 16 + kg * 4 + rg;
                int px = bx * 64 + pw * 32 + pt * 16 + r15;
                float v = acc[ct][pt][rg] + bias[co];
                outp[(size_t)(bz * 128 + co) * 3136 + px] = lrelu(v);
            }
}

// ---------------------------------------------------------------------------
// x -> x_pad [32*3][228][228], 2-pixel zero border.
// ---------------------------------------------------------------------------
__global__ __launch_bounds__(256) void pad_x_k(const float* __restrict__ x,
                                               float* __restrict__ xp) {
    int blk = blockIdx.x;              // 32*3*57
    int r4 = blk % 57, ic = blk / 57;
    int wid = threadIdx.x >> 6, lane = threadIdx.x & 63;
    int row = r4 * 4 + wid;
    const float* __restrict__ src = x + (size_t)ic * 224 * 224 + (size_t)(row - 2) * 224;
    float* __restrict__ dst = xp + (size_t)ic * 228 * 228 + (size_t)row * 228;
    bool rok = (row >= 2) && (row < 226);
    for (int c = lane; c < 228; c += 64) {
        float v = 0.0f;
        if (rok && c >= 2 && c < 226) v = src[c - 2];
        dst[c] = v;
    }
}

// c1p plane = 116 x 120; data ow at layout col ow+4 (border cols 2,3,116,117).
__global__ __launch_bounds__(256) void zb_c1p_k(float* __restrict__ p) {
    float* base = p + (size_t)blockIdx.x * (116 * 120);
    for (int t = threadIdx.x; t < 928; t += 256) {
        int idx;
        if (t < 480) {
            int r = t / 120, c = t - r * 120;
            int row = (r < 2) ? r : r + 112;
            idx = row * 120 + c;
        } else {
            int s = t - 480;
            int r = s >> 2, c = s & 3;
            int col = (c < 2) ? (c + 2) : (c + 114);
            idx = (r + 2) * 120 + col;
        }
        base[idx] = 0.0f;
    }
}

// c2p plane = 58 x 64; data ow at layout col ow+4 (border cols 3,60).
__global__ __launch_bounds__(64) void zb_c2p_k(float* __restrict__ p) {
    float* base = p + (size_t)blockIdx.x * (58 * 64);
    for (int t = threadIdx.x; t < 240; t += 64) {
        int idx;
        if (t < 128) {
            int r = t >> 6, c = t & 63;
            idx = (r ? 57 : 0) * 64 + c;
        } else {
            int s = t - 128;
            int r = (s >> 1) + 1;
            idx = r * 64 + ((s & 1) ? 60 : 3);
        }
        base[idx] = 0.0f;
    }
}

// ---------------------------------------------------------------------------
// ROI bilinear sampling (unchanged). S[b][c][r][p] == reference reshape quirk.
// ---------------------------------------------------------------------------
__global__ __launch_bounds__(256) void roi_k(const float* __restrict__ feat,
                                             const float* __restrict__ roi,
                                             float* __restrict__ S) {
    int b = blockIdx.x >> 5;
    int r = blockIdx.x & 31;
    const float* rr = roi + (size_t)(b * 32 + r) * 7;

    __shared__ int   offA[100], offB[100], offC[100], offD[100];
    __shared__ float wA[100], wB[100], wC[100], wD[100];

    int tid = threadIdx.x;
    if (tid < 100) {
        int i = tid / 10, j = tid % 10;
        float cx = rr[0], cy = rr[1];
        float W1 = rr[2], W2 = rr[3], H1 = rr[4], H2 = rr[5], psi = rr[6];
        float offx = ((float)j - 4.5f) / 10.0f;
        float offy = ((float)i - 4.5f) / 10.0f;
        float gx = offx * (W1 + W2) - (W1 - W2) * 0.5f;
        float gy = offy * (H1 + H2) - (H1 - H2) * 0.5f;
        float sn = sinf(psi), cs = cosf(psi);
        float xs = gx * cs + gy * sn + cx;
        float ys = -gx * sn + gy * cs + cy;

        float x0f = floorf(xs), y0f = floorf(ys);
        int x0 = (int)x0f, x1 = x0 + 1;
        int y0 = (int)y0f, y1 = y0 + 1;
        x0 = min(max(x0, 0), 55); x1 = min(max(x1, 0), 55);
        y0 = min(max(y0, 0), 55); y1 = min(max(y1, 0), 55);
        float fx0 = (float)x0, fx1 = (float)x1;
        float fy0 = (float)y0, fy1 = (float)y1;
        float step = (fx1 - fx0) * (fy1 - fy0);
        step = fminf(fmaxf(step, 0.001f), 2.0f);
        float inv = 1.0f / step;
        wA[tid] = (fx1 - xs) * (fy1 - ys) * inv;
        wB[tid] = (fx1 - xs) * (ys - fy0) * inv;
        wC[tid] = (xs - fx0) * (fy1 - ys) * inv;
        wD[tid] = (xs - fx0) * (ys - fy0) * inv;
        offA[tid] = y0 * 56 + x0;
        offB[tid] = y1 * 56 + x0;
        offC[tid] = y0 * 56 + x1;
        offD[tid] = y1 * 56 + x1;
    }
    __syncthreads();

    const float* __restrict__ fb = feat + (size_t)b * 128 * 3136;
    float* __restrict__ outb = S + ((size_t)b * 128 * 32 + r) * 100;
    int c = tid / 100;
    int p = tid - c * 100;
    for (int t = tid; t < 12800; t += 256) {
        const float* f = fb + c * 3136;
        float v = wA[p] * f[offA[p]] + wB[p] * f[offB[p]] +
                  wC[p] * f[offC[p]] + wD[p] * f[offD[p]];
        outb[(size_t)c * 3200 + p] = v;
        p += 56; c += 2;
        if (p >= 100) { p -= 100; ++c; }
    }
}

// ---------------------------------------------------------------------------
// FC split-K GEMM v6: 128x128 tile, 8x8 micro, BK=16, ksplit=32.
// ---------------------------------------------------------------------------
__global__ __launch_bounds__(256, 2) void fc2_k(const float* __restrict__ A,
                                                const float* __restrict__ B,
                                                float* __restrict__ part) {
    constexpr int PAD = 132;
    __shared__ float sm[2 * 2 * 16 * PAD];

    const int tid = threadIdx.x;
    const int bn = blockIdx.x, bm = blockIdx.y, ks = blockIdx.z;
    const int tx = tid & 15, ty = tid >> 4;
    const int m0 = tid >> 2;
    const int kq = tid & 3;

    const int pc0 = (((m0 >> 2) & 1) * 16 + (m0 >> 3)) * 4 + (m0 & 3);

    const float* __restrict__ a0 = A + (size_t)(bm * 128 + m0) * 12800 + ks * 400 + kq * 4;
    const float* __restrict__ a1 = a0 + (size_t)64 * 12800;
    const float* __restrict__ b0 = B + (size_t)(bn * 128 + m0) * 12800 + ks * 400 + kq * 4;
    const float* __restrict__ b1 = b0 + (size_t)64 * 12800;

    float4 ar0 = *(const float4*)a0;
    float4 ar1 = *(const float4*)a1;
    float4 br0 = *(const float4*)b0;
    float4 br1 = *(const float4*)b1;

    float acc[8][8] = {};

    for (int it = 0; it < 25; ++it) {
        const int p = it & 1;
        float* __restrict__ As = sm + p * (2 * 16 * PAD);
        float* __restrict__ Ws = As + 16 * PAD;
        const int base = kq * 4 * PAD + pc0;
        As[base]                = ar0.x; As[base + PAD]          = ar0.y;
        As[base + 2 * PAD]      = ar0.z; As[base + 3 * PAD]      = ar0.w;
        As[base + 32]           = ar1.x; As[base + 32 + PAD]     = ar1.y;
        As[base + 32 + 2 * PAD] = ar1.z; As[base + 32 + 3 * PAD] = ar1.w;
        Ws[base]                = br0.x; Ws[base + PAD]          = br0.y;
        Ws[base + 2 * PAD]      = br0.z; Ws[base + 3 * PAD]      = br0.w;
        Ws[base + 32]           = br1.x; Ws[base + 32 + PAD]     = br1.y;
        Ws[base + 32 + 2 * PAD] = br1.z; Ws[base + 32 + 3 * PAD] = br1.w;
        __syncthreads();
        if (it + 1 < 25) {
            ar0 = *(const float4*)(a0 + (it + 1) * 16);
            ar1 = *(const float4*)(a1 + (it + 1) * 16);
            br0 = *(const float4*)(b0 + (it + 1) * 16);
            br1 = *(const float4*)(b1 + (it + 1) * 16);
        }
#pragma unroll
        for (int k = 0; k < 16; ++k) {
            float4 aL = *(const float4*)&As[k * PAD + ty * 4];
            float4 aH = *(const float4*)&As[k * PAD + 64 + ty * 4];
            float4 bL = *(const float4*)&Ws[k * PAD + tx * 4];
            float4 bH = *(const float4*)&Ws[k * PAD + 64 + tx * 4];
            float a[8] = {aL.x, aL.y, aL.z, aL.w, aH.x, aH.y, aH.z, aH.w};
            float b[8] = {bL.x, bL.y, bL.z, bL.w, bH.x, bH.y, bH.z, bH.w};
#pragma unroll
            for (int j = 0; j < 8; ++j)
#pragma unroll
                for (int i = 0; i < 8; ++i)
                    acc[j][i] += a[j] * b[i];
        }
    }

    float* __restrict__ po = part + (size_t)ks * 262144
                                  + (size_t)(bm * 128 + ty * 8) * 256 + bn * 128 + tx * 8;
#pragma unroll
    for (int j = 0; j < 8; ++j) {
        *(float4*)(po + (size_t)j * 256)     = make_float4(acc[j][0], acc[j][1], acc[j][2], acc[j][3]);
        *(float4*)(po + (size_t)j * 256 + 4) = make_float4(acc[j][4], acc[j][5], acc[j][6], acc[j][7]);
    }
}

__global__ __launch_bounds__(256) void fc2_reduce_k(const float* __restrict__ part,
                                                    const float* __restrict__ bias,
                                                    float* __restrict__ out) {
    int i = blockIdx.x * 256 + threadIdx.x;   // 0..262143
    float s = bias[i & 255];
    for (int ks = 0; ks < 32; ++ks) s += part[(size_t)ks * 262144 + i];
    out[i] = s;
}

// ---------------------------------------------------------------------------
extern "C" void kernel_launch(void* const* d_in, const int* in_sizes, int n_in,
                              void* d_out, int out_size, void* d_ws, size_t ws_size,
                              hipStream_t stream) {
    const float* x   = (const float*)d_in[0];
    const float* ROI = (const float*)d_in[1];
    const float* w1  = (const float*)d_in[2];
    const float* b1  = (const float*)d_in[3];
    const float* w2  = (const float*)d_in[4];
    const float* b2  = (const float*)d_in[5];
    const float* w3  = (const float*)d_in[6];
    const float* b3  = (const float*)d_in[7];
    const float* fcw = (const float*)d_in[8];
    const float* fcb = (const float*)d_in[9];
    float* out = (float*)d_out;

    char* ws = (char*)d_ws;
    // Workspace (<= 128.45 MB proven safe):
    //  c1p  [0,           57,016,320)  conv1 -> conv2
    //  c2p  [57,016,320,  87,425,024)  conv2 -> conv3
    //  xpad [87,425,024, 107,386,880)  pad  -> conv1          (dead after conv1)
    //  wT1/2/3 [107,386,880, 107,896,832)                     (dead after split)
    //  c2s  [87,425,024, 117,833,728)  packed c2p  (lives over dead xpad/wT;
    //                                  NOTE: split wT3->w3s BEFORE c2p->c2s,
    //                                  since wT3 sits inside the c2s range)
    //  w3s  [117,833,728, 118,128,640) packed wT3
    //  c3   [0,           51,380,224)  conv3 -> roi      (c1p dead)
    //  S    [57,016,320, 109,445,120)  roi -> fc         (c2p/c2s dead)
    //  part [0,           33,554,432)  fc -> reduce      (c3 dead after roi)
    float* c1p  = (float*)(ws);
    float* c2p  = (float*)(ws + 57016320);
    float* xpad = (float*)(ws + 87425024);
    float* wT1  = (float*)(ws + 107386880);
    float* wT2  = (float*)(ws + 107397120);
    float* wT3  = (float*)(ws + 107601920);
    float* c3   = (float*)(ws);
    float* S    = (float*)(ws + 57016320);
    float* part = (float*)(ws);
    unsigned* c2s = (unsigned*)(ws + 87425024);
    unsigned* w3s = (unsigned*)(ws + 117833728);

    wtr_k<32,  75, 80 ><<<10,  256, 0, stream>>>(w1, wT1);
    wtr_k<64,  800, 800><<<200, 256, 0, stream>>>(w2, wT2);
    wtr_k<128, 576, 576><<<288, 256, 0, stream>>>(w3, wT3);
    pad_x_k<<<32 * 3 * 57, 256, 0, stream>>>(x, xpad);
    zb_c1p_k<<<1024, 256, 0, stream>>>(c1p);
    zb_c2p_k<<<2048, 64, 0, stream>>>(c2p);

    // conv1: 32co x 128px, 4x4 micro, 256 thr, BK=16, MINW=4 (R9 config)
    conv_gemm_k<3, 2, 5, 5, 75, 80, 228, 228, 0, 112, 12544,
                32, 128, 4, 4, 116, 120, 2, 4, 4, 256, 16>
        <<<3136, 256, 0, stream>>>(xpad, wT1, b1, c1p);
    // conv2: 64co x 128px, 8x4 micro, 256 thr, MINW=3 (R9 config)
    conv_gemm_k<32, 2, 5, 5, 800, 800, 116, 120, 2, 56, 3136,
                64, 128, 8, 4, 58, 64, 1, 4, 3, 256, 16>
        <<<784, 256, 0, stream>>>(c1p, wT2, b2, c2p);

    // conv3 on MFMA: split-pack inputs (wT3 FIRST — it lies inside c2s range)
    split_pack_k<<<288,  256, 0, stream>>>(wT3, w3s, 73728);
    split_pack_k<<<4096, 256, 0, stream>>>(c2p, c2s, 7602176);
    conv3_mfma_k<<<dim3(49, 2, 32), 256, 0, stream>>>(c2s, w3s, b3, c3);

    // ROI sampling -> S[b][c][r][p]
    roi_k<<<1024, 256, 0, stream>>>(c3, ROI, S);
    // FC: split-K 32 + reduce
    fc2_k<<<dim3(2, 8, 32), 256, 0, stream>>>(S, fcw, part);
    fc2_reduce_k<<<1024, 256, 0, stream>>>(part, fcb, out);
}

// Round 6
// 524.966 us; speedup vs baseline: 1.2238x; 1.2238x over previous
//
#include <hip/hip_runtime.h>
#include <hip/hip_bf16.h>

#define LEAK 0.2f

__device__ __forceinline__ float lrelu(float a) { return a > 0.0f ? a : LEAK * a; }

typedef __attribute__((ext_vector_type(8))) short short8;
typedef __attribute__((ext_vector_type(4))) float f32x4;

// bf16 RNE rounding done manually (no dependence on __hip_bfloat16 ABI).
__device__ __forceinline__ unsigned short bf16_hi_bits(float x) {
    unsigned u = __builtin_bit_cast(unsigned, x);
    unsigned r = u + 0x7fffu + ((u >> 16) & 1u);
    return (unsigned short)(r >> 16);
}
__device__ __forceinline__ float bf16_to_f32(unsigned short h) {
    unsigned u = ((unsigned)h) << 16;
    return __builtin_bit_cast(float, u);
}

// ---------------------------------------------------------------------------
// Implicit-GEMM conv + leaky ReLU (fp32 vector path — conv1 only now).
// ---------------------------------------------------------------------------
template<int CI, int ST, int KH, int KW, int KIN, int KP,
         int PIH, int PIW, int LP, int OW, int PPI,
         int CO, int NT, int MR, int NR, int OSH, int OSW, int OR0, int OC0,
         int MINW, int NTHR, int BK>
__global__ __launch_bounds__(NTHR, MINW) void conv_gemm_k(
    const float* __restrict__ in,    // padded input [img*CI + ci][PIH][PIW]
    const float* __restrict__ wT,    // [KP][CO]
    const float* __restrict__ bias,
    float* __restrict__ out)
{
    constexpr int KT  = KP / BK;
    constexpr int TXW = NT / 4;         // B staging pixel-quads per k-row
    constexpr int TXN = NT / NR;        // compute columns
    constexpr int BT  = BK * NT / 4;
    constexpr int AT  = BK * CO / 4;
    constexpr int BI  = (BT + NTHR - 1) / NTHR;
    constexpr int AI  = (AT + NTHR - 1) / NTHR;
    constexpr int ASZ = BK * CO;
    constexpr int BSZ = BK * NT;

    __shared__ float sm[2 * ASZ + 2 * BSZ];

    const int tid = threadIdx.x;
    const int bx  = blockIdx.x;
    const int tx  = tid % TXN;
    const int ty  = tid / TXN;

    // ---- per-thread staging geometry (K-independent) ----
    int bofs[BI], bkl[BI], bcol[BI];
#pragma unroll
    for (int q = 0; q < BI; ++q) {
        int task = tid + q * NTHR;
        if ((BT % NTHR == 0) || task < BT) {
            int kl  = task / TXW;
            int pxq = task % TXW;
            int px0 = bx * NT + pxq * 4;
            int img = px0 / PPI;
            int n   = px0 % PPI;
            int oh  = n / OW, ow = n % OW;
            bofs[q] = ((img * CI) * PIH + oh * ST) * PIW + ow * ST + LP;
            bkl[q]  = kl;
            bcol[q] = (NR == 8) ? (((pxq & 1) * (TXW / 2) + (pxq >> 1)) * 4)
                                : (pxq * 4);
        }
    }

    float  br[BI][4];
    float4 ar[AI];

    auto gather = [&](int it) {
        int k0 = it * BK;
#pragma unroll
        for (int q = 0; q < BI; ++q) {
            int task = tid + q * NTHR;
            if ((BT % NTHR == 0) || task < BT) {
                int k = k0 + bkl[q];
                if (KP > KIN) k = min(k, KIN - 1);   // padded-K tail (weights 0)
                int ci  = k / (KH * KW);
                int rem = k - ci * (KH * KW);
                int kh  = rem / KW;
                int kw  = rem - kh * KW;
                const float* __restrict__ s = in + bofs[q] + (ci * PIH + kh) * PIW + kw;
                br[q][0] = s[0]; br[q][1] = s[ST]; br[q][2] = s[2 * ST]; br[q][3] = s[3 * ST];
            }
        }
#pragma unroll
        for (int p = 0; p < AI; ++p) {
            int task = tid + p * NTHR;
            if ((AT % NTHR == 0) || task < AT)
                ar[p] = *(const float4*)&wT[(size_t)k0 * CO + task * 4];
        }
    };

    float acc[MR][NR];
#pragma unroll
    for (int j = 0; j < MR; ++j) {
        float bv = bias[ty * MR + j];
#pragma unroll
        for (int i = 0; i < NR; ++i) acc[j][i] = bv;
    }

    gather(0);
    for (int it = 0; it < KT; ++it) {
        const int p = it & 1;
        float* __restrict__ Asb = sm + p * ASZ;
        float* __restrict__ Bsb = sm + 2 * ASZ + p * BSZ;
#pragma unroll
        for (int pa = 0; pa < AI; ++pa) {
            int task = tid + pa * NTHR;
            if ((AT % NTHR == 0) || task < AT)
                *(float4*)&Asb[task * 4] = ar[pa];
        }
#pragma unroll
        for (int q = 0; q < BI; ++q) {
            int task = tid + q * NTHR;
            if ((BT % NTHR == 0) || task < BT)
                *(float4*)&Bsb[bkl[q] * NT + bcol[q]] =
                    make_float4(br[q][0], br[q][1], br[q][2], br[q][3]);
        }
        __syncthreads();
        if (it + 1 < KT) gather(it + 1);
#pragma unroll
        for (int k = 0; k < BK; ++k) {
            float b[NR], a[MR];
            if (NR == 8) {
                *(float4*)&b[0] = *(const float4*)&Bsb[k * NT + tx * 4];
                *(float4*)&b[4] = *(const float4*)&Bsb[k * NT + NT / 2 + tx * 4];
            } else {
#pragma unroll
                for (int i = 0; i < NR / 4; ++i)
                    *(float4*)&b[4 * i] = *(const float4*)&Bsb[k * NT + tx * NR + 4 * i];
            }
#pragma unroll
            for (int j = 0; j < MR / 4; ++j)
                *(float4*)&a[4 * j] = *(const float4*)&Asb[k * CO + ty * MR + 4 * j];
#pragma unroll
            for (int j = 0; j < MR; ++j)
#pragma unroll
                for (int i = 0; i < NR; ++i)
                    acc[j][i] += a[j] * b[i];
        }
    }

    {
        int pxs = bx * NT + tx * NR;
        int img = pxs / PPI;
        int n   = pxs % PPI;
        int oh  = n / OW, ow = n % OW;
#pragma unroll
        for (int j = 0; j < MR; ++j) {
            int co = ty * MR + j;
            size_t off = (((size_t)img * CO + co) * OSH + (oh + OR0)) * OSW + (ow + OC0);
#pragma unroll
            for (int q = 0; q < NR / 4; ++q) {
                float4 v = make_float4(lrelu(acc[j][4 * q + 0]), lrelu(acc[j][4 * q + 1]),
                                       lrelu(acc[j][4 * q + 2]), lrelu(acc[j][4 * q + 3]));
                *(float4*)&out[off + 4 * q] = v;
            }
        }
    }
}

// ---------------------------------------------------------------------------
// Weight transpose fp32 (conv1): wT[k][co] = w[co][k], K padded with zeros.
// ---------------------------------------------------------------------------
template<int CO, int KIN, int KP>
__global__ __launch_bounds__(256) void wtr_k(const float* __restrict__ w,
                                             float* __restrict__ wT) {
    int i = blockIdx.x * 256 + threadIdx.x;
    if (i >= KP * CO) return;
    int k = i / CO, co = i % CO;
    wT[i] = (k < KIN) ? w[(size_t)co * KIN + k] : 0.0f;
}

// Weight transpose + bf16 hi/lo pack (conv2/conv3 MFMA path).
template<int CO, int KIN, int KP>
__global__ __launch_bounds__(256) void wtr_pack_k(const float* __restrict__ w,
                                                  unsigned* __restrict__ wTp) {
    int i = blockIdx.x * 256 + threadIdx.x;
    if (i >= KP * CO) return;
    int k = i / CO, co = i % CO;
    float x = (k < KIN) ? w[(size_t)co * KIN + k] : 0.0f;
    unsigned short h = bf16_hi_bits(x);
    float lo = x - bf16_to_f32(h);
    wTp[i] = (unsigned)h | ((unsigned)bf16_hi_bits(lo) << 16);
}

// ---------------------------------------------------------------------------
// In-place pack fp32 -> dword {bf16 hi (low16), bf16 lo (high16)}. x ~= hi+lo.
// Per-element read-then-write at the same index: race-free in place.
// ---------------------------------------------------------------------------
__global__ __launch_bounds__(256) void split_pack_k(const float* __restrict__ src,
                                                    unsigned* __restrict__ dst, int n) {
    for (int i = blockIdx.x * 256 + threadIdx.x; i < n; i += gridDim.x * 256) {
        float x = src[i];
        unsigned short h = bf16_hi_bits(x);
        float lo = x - bf16_to_f32(h);
        unsigned short l = bf16_hi_bits(lo);
        dst[i] = (unsigned)h | ((unsigned)l << 16);
    }
}

// ---------------------------------------------------------------------------
// Conv as bf16 hi/lo split-GEMM on MFMA (conv2 and conv3).
// out[co][px] = lrelu(bias + sum_k w[k][co]*act[k][px]); product ~ HH+HL+LH.
// Block: 64co x 64px, 4 waves, each wave 32co x 32px = 2x2 16x16 frags.
// BK=32 = one mfma_f32_16x16x32_bf16 K-chunk; double-buffered LDS;
// rows padded to 40 shorts (80B stride) -> <=2-way bank aliasing (free).
// Frag maps (m89/m91, HW-verified in R5): A[l&15][(l>>4)*8+j],
// B[(l>>4)*8+j][l&15], C/D col=lane&15 (px), row=(lane>>4)*4+reg (co).
// ---------------------------------------------------------------------------
template<int CI, int ST, int KH, int KW, int KP,
         int PIH, int PIW, int LP,
         int CO, int OW, int OSH, int OSW, int OR0, int OC0>
__global__ __launch_bounds__(256, 2) void conv_mfma_k(
    const unsigned* __restrict__ src,   // packed act [img*CI+ci][PIH][PIW]
    const unsigned* __restrict__ wp,    // packed wT  [KP][CO]
    const float* __restrict__ bias,
    float* __restrict__ outp)
{
    constexpr int KT = KP / 32;
    __shared__ short8 smq[2560];        // 2 buf x 4 arrays x 64 rows x 40 shorts
    short* const lds = (short*)smq;

    const int tid  = threadIdx.x;
    const int lane = tid & 63;
    const int wv   = tid >> 6;          // wave 0..3
    const int bx   = blockIdx.x;        // 49 px tiles
    const int by   = blockIdx.y;        // CO/64 co tiles
    const int bz   = blockIdx.z;        // 32 imgs

    const int row = lane;               // staging row; k-slot = wave (8 k each)
    const int n   = bx * 64 + row;      // 0..3135
    const int oh  = n / OW, ow = n % OW;
    const int bbase = ((bz * CI) * PIH + oh * ST) * PIW + ow * ST + LP;
    const int coA   = by * 64 + row;

    unsigned Au[8], Bu[8];
    auto gather = [&](int it) {
        int k0 = it * 32 + wv * 8;
#pragma unroll
        for (int j = 0; j < 8; ++j) {
            int k  = k0 + j;
            Au[j]  = wp[k * CO + coA];
            int ci = k / (KH * KW), r = k - ci * (KH * KW);
            int kh = r / KW, kw = r - kh * KW;
            Bu[j]  = src[bbase + (ci * PIH + kh) * PIW + kw];
        }
    };

    f32x4 acc[2][2] = {};

    const int cw = wv & 1, pw = wv >> 1;
    const int r15 = lane & 15, kg = lane >> 4;

    gather(0);
    for (int it = 0; it < KT; ++it) {
        const int p = it & 1;
        {
            short8 ah, al, bh, bl;
#pragma unroll
            for (int j = 0; j < 8; ++j) {
                ah[j] = (short)(Au[j] & 0xffffu);
                al[j] = (short)(Au[j] >> 16);
                bh[j] = (short)(Bu[j] & 0xffffu);
                bl[j] = (short)(Bu[j] >> 16);
            }
            const int idx = row * 40 + wv * 8;
            *(short8*)&lds[(p * 4 + 0) * 2560 + idx] = ah;
            *(short8*)&lds[(p * 4 + 1) * 2560 + idx] = al;
            *(short8*)&lds[(p * 4 + 2) * 2560 + idx] = bh;
            *(short8*)&lds[(p * 4 + 3) * 2560 + idx] = bl;
        }
        __syncthreads();
        if (it + 1 < KT) gather(it + 1);

        const short* AsH = lds + (p * 4 + 0) * 2560;
        const short* AsL = lds + (p * 4 + 1) * 2560;
        const short* BsH = lds + (p * 4 + 2) * 2560;
        const short* BsL = lds + (p * 4 + 3) * 2560;
        short8 aH[2], aL[2], bH[2], bL[2];
#pragma unroll
        for (int tq = 0; tq < 2; ++tq) {
            const int ra = (cw * 32 + tq * 16 + r15) * 40 + kg * 8;
            aH[tq] = *(const short8*)&AsH[ra];
            aL[tq] = *(const short8*)&AsL[ra];
            const int rb = (pw * 32 + tq * 16 + r15) * 40 + kg * 8;
            bH[tq] = *(const short8*)&BsH[rb];
            bL[tq] = *(const short8*)&BsL[rb];
        }
#pragma unroll
        for (int ct = 0; ct < 2; ++ct)
#pragma unroll
            for (int pt = 0; pt < 2; ++pt) {
                acc[ct][pt] = __builtin_amdgcn_mfma_f32_16x16x32_bf16(aH[ct], bH[pt], acc[ct][pt], 0, 0, 0);
                acc[ct][pt] = __builtin_amdgcn_mfma_f32_16x16x32_bf16(aH[ct], bL[pt], acc[ct][pt], 0, 0, 0);
                acc[ct][pt] = __builtin_amdgcn_mfma_f32_16x16x32_bf16(aL[ct], bH[pt], acc[ct][pt], 0, 0, 0);
            }
    }

    // C/D: col = lane&15 -> px, row = (lane>>4)*4+reg -> co
#pragma unroll
    for (int ct = 0; ct < 2; ++ct)
#pragma unroll
        for (int pt = 0; pt < 2; ++pt)
#pragma unroll
            for (int rg = 0; rg < 4; ++rg) {
                int co = by * 64 + cw * 32 + ct * 16 + kg * 4 + rg;
                int px = bx * 64 + pw * 32 + pt * 16 + r15;
                int poh = px / OW, pow_ = px % OW;
                float v = acc[ct][pt][rg] + bias[co];
                outp[((size_t)(bz * CO + co) * OSH + (poh + OR0)) * OSW + (pow_ + OC0)] = lrelu(v);
            }
}

// ---------------------------------------------------------------------------
// x -> x_pad [32*3][228][228], 2-pixel zero border.
// ---------------------------------------------------------------------------
__global__ __launch_bounds__(256) void pad_x_k(const float* __restrict__ x,
                                               float* __restrict__ xp) {
    int blk = blockIdx.x;              // 32*3*57
    int r4 = blk % 57, ic = blk / 57;
    int wid = threadIdx.x >> 6, lane = threadIdx.x & 63;
    int row = r4 * 4 + wid;
    const float* __restrict__ src = x + (size_t)ic * 224 * 224 + (size_t)(row - 2) * 224;
    float* __restrict__ dst = xp + (size_t)ic * 228 * 228 + (size_t)row * 228;
    bool rok = (row >= 2) && (row < 226);
    for (int c = lane; c < 228; c += 64) {
        float v = 0.0f;
        if (rok && c >= 2 && c < 226) v = src[c - 2];
        dst[c] = v;
    }
}

// c1p plane = 116 x 120; data ow at layout col ow+4 (border cols 2,3,116,117).
__global__ __launch_bounds__(256) void zb_c1p_k(float* __restrict__ p) {
    float* base = p + (size_t)blockIdx.x * (116 * 120);
    for (int t = threadIdx.x; t < 928; t += 256) {
        int idx;
        if (t < 480) {
            int r = t / 120, c = t - r * 120;
            int row = (r < 2) ? r : r + 112;
            idx = row * 120 + c;
        } else {
            int s = t - 480;
            int r = s >> 2, c = s & 3;
            int col = (c < 2) ? (c + 2) : (c + 114);
            idx = (r + 2) * 120 + col;
        }
        base[idx] = 0.0f;
    }
}

// c2p plane = 58 x 64; data ow at layout col ow+4 (border cols 3,60).
__global__ __launch_bounds__(64) void zb_c2p_k(float* __restrict__ p) {
    float* base = p + (size_t)blockIdx.x * (58 * 64);
    for (int t = threadIdx.x; t < 240; t += 64) {
        int idx;
        if (t < 128) {
            int r = t >> 6, c = t & 63;
            idx = (r ? 57 : 0) * 64 + c;
        } else {
            int s = t - 128;
            int r = (s >> 1) + 1;
            idx = r * 64 + ((s & 1) ? 60 : 3);
        }
        base[idx] = 0.0f;
    }
}

// ---------------------------------------------------------------------------
// ROI bilinear sampling (unchanged). S[b][c][r][p] == reference reshape quirk.
// ---------------------------------------------------------------------------
__global__ __launch_bounds__(256) void roi_k(const float* __restrict__ feat,
                                             const float* __restrict__ roi,
                                             float* __restrict__ S) {
    int b = blockIdx.x >> 5;
    int r = blockIdx.x & 31;
    const float* rr = roi + (size_t)(b * 32 + r) * 7;

    __shared__ int   offA[100], offB[100], offC[100], offD[100];
    __shared__ float wA[100], wB[100], wC[100], wD[100];

    int tid = threadIdx.x;
    if (tid < 100) {
        int i = tid / 10, j = tid % 10;
        float cx = rr[0], cy = rr[1];
        float W1 = rr[2], W2 = rr[3], H1 = rr[4], H2 = rr[5], psi = rr[6];
        float offx = ((float)j - 4.5f) / 10.0f;
        float offy = ((float)i - 4.5f) / 10.0f;
        float gx = offx * (W1 + W2) - (W1 - W2) * 0.5f;
        float gy = offy * (H1 + H2) - (H1 - H2) * 0.5f;
        float sn = sinf(psi), cs = cosf(psi);
        float xs = gx * cs + gy * sn + cx;
        float ys = -gx * sn + gy * cs + cy;

        float x0f = floorf(xs), y0f = floorf(ys);
        int x0 = (int)x0f, x1 = x0 + 1;
        int y0 = (int)y0f, y1 = y0 + 1;
        x0 = min(max(x0, 0), 55); x1 = min(max(x1, 0), 55);
        y0 = min(max(y0, 0), 55); y1 = min(max(y1, 0), 55);
        float fx0 = (float)x0, fx1 = (float)x1;
        float fy0 = (float)y0, fy1 = (float)y1;
        float step = (fx1 - fx0) * (fy1 - fy0);
        step = fminf(fmaxf(step, 0.001f), 2.0f);
        float inv = 1.0f / step;
        wA[tid] = (fx1 - xs) * (fy1 - ys) * inv;
        wB[tid] = (fx1 - xs) * (ys - fy0) * inv;
        wC[tid] = (xs - fx0) * (fy1 - ys) * inv;
        wD[tid] = (xs - fx0) * (ys - fy0) * inv;
        offA[tid] = y0 * 56 + x0;
        offB[tid] = y1 * 56 + x0;
        offC[tid] = y0 * 56 + x1;
        offD[tid] = y1 * 56 + x1;
    }
    __syncthreads();

    const float* __restrict__ fb = feat + (size_t)b * 128 * 3136;
    float* __restrict__ outb = S + ((size_t)b * 128 * 32 + r) * 100;
    int c = tid / 100;
    int p = tid - c * 100;
    for (int t = tid; t < 12800; t += 256) {
        const float* f = fb + c * 3136;
        float v = wA[p] * f[offA[p]] + wB[p] * f[offB[p]] +
                  wC[p] * f[offC[p]] + wD[p] * f[offD[p]];
        outb[(size_t)c * 3200 + p] = v;
        p += 56; c += 2;
        if (p >= 100) { p -= 100; ++c; }
    }
}

// ---------------------------------------------------------------------------
// FC split-K GEMM v6: 128x128 tile, 8x8 micro, BK=16, ksplit=32.
// ---------------------------------------------------------------------------
__global__ __launch_bounds__(256, 2) void fc2_k(const float* __restrict__ A,
                                                const float* __restrict__ B,
                                                float* __restrict__ part) {
    constexpr int PAD = 132;
    __shared__ float sm[2 * 2 * 16 * PAD];

    const int tid = threadIdx.x;
    const int bn = blockIdx.x, bm = blockIdx.y, ks = blockIdx.z;
    const int tx = tid & 15, ty = tid >> 4;
    const int m0 = tid >> 2;
    const int kq = tid & 3;

    const int pc0 = (((m0 >> 2) & 1) * 16 + (m0 >> 3)) * 4 + (m0 & 3);

    const float* __restrict__ a0 = A + (size_t)(bm * 128 + m0) * 12800 + ks * 400 + kq * 4;
    const float* __restrict__ a1 = a0 + (size_t)64 * 12800;
    const float* __restrict__ b0 = B + (size_t)(bn * 128 + m0) * 12800 + ks * 400 + kq * 4;
    const float* __restrict__ b1 = b0 + (size_t)64 * 12800;

    float4 ar0 = *(const float4*)a0;
    float4 ar1 = *(const float4*)a1;
    float4 br0 = *(const float4*)b0;
    float4 br1 = *(const float4*)b1;

    float acc[8][8] = {};

    for (int it = 0; it < 25; ++it) {
        const int p = it & 1;
        float* __restrict__ As = sm + p * (2 * 16 * PAD);
        float* __restrict__ Ws = As + 16 * PAD;
        const int base = kq * 4 * PAD + pc0;
        As[base]                = ar0.x; As[base + PAD]          = ar0.y;
        As[base + 2 * PAD]      = ar0.z; As[base + 3 * PAD]      = ar0.w;
        As[base + 32]           = ar1.x; As[base + 32 + PAD]     = ar1.y;
        As[base + 32 + 2 * PAD] = ar1.z; As[base + 32 + 3 * PAD] = ar1.w;
        Ws[base]                = br0.x; Ws[base + PAD]          = br0.y;
        Ws[base + 2 * PAD]      = br0.z; Ws[base + 3 * PAD]      = br0.w;
        Ws[base + 32]           = br1.x; Ws[base + 32 + PAD]     = br1.y;
        Ws[base + 32 + 2 * PAD] = br1.z; Ws[base + 32 + 3 * PAD] = br1.w;
        __syncthreads();
        if (it + 1 < 25) {
            ar0 = *(const float4*)(a0 + (it + 1) * 16);
            ar1 = *(const float4*)(a1 + (it + 1) * 16);
            br0 = *(const float4*)(b0 + (it + 1) * 16);
            br1 = *(const float4*)(b1 + (it + 1) * 16);
        }
#pragma unroll
        for (int k = 0; k < 16; ++k) {
            float4 aL = *(const float4*)&As[k * PAD + ty * 4];
            float4 aH = *(const float4*)&As[k * PAD + 64 + ty * 4];
            float4 bL = *(const float4*)&Ws[k * PAD + tx * 4];
            float4 bH = *(const float4*)&Ws[k * PAD + 64 + tx * 4];
            float a[8] = {aL.x, aL.y, aL.z, aL.w, aH.x, aH.y, aH.z, aH.w};
            float b[8] = {bL.x, bL.y, bL.z, bL.w, bH.x, bH.y, bH.z, bH.w};
#pragma unroll
            for (int j = 0; j < 8; ++j)
#pragma unroll
                for (int i = 0; i < 8; ++i)
                    acc[j][i] += a[j] * b[i];
        }
    }

    float* __restrict__ po = part + (size_t)ks * 262144
                                  + (size_t)(bm * 128 + ty * 8) * 256 + bn * 128 + tx * 8;
#pragma unroll
    for (int j = 0; j < 8; ++j) {
        *(float4*)(po + (size_t)j * 256)     = make_float4(acc[j][0], acc[j][1], acc[j][2], acc[j][3]);
        *(float4*)(po + (size_t)j * 256 + 4) = make_float4(acc[j][4], acc[j][5], acc[j][6], acc[j][7]);
    }
}

__global__ __launch_bounds__(256) void fc2_reduce_k(const float* __restrict__ part,
                                                    const float* __restrict__ bias,
                                                    float* __restrict__ out) {
    int i = blockIdx.x * 256 + threadIdx.x;   // 0..262143
    float s = bias[i & 255];
    for (int ks = 0; ks < 32; ++ks) s += part[(size_t)ks * 262144 + i];
    out[i] = s;
}

// ---------------------------------------------------------------------------
extern "C" void kernel_launch(void* const* d_in, const int* in_sizes, int n_in,
                              void* d_out, int out_size, void* d_ws, size_t ws_size,
                              hipStream_t stream) {
    const float* x   = (const float*)d_in[0];
    const float* ROI = (const float*)d_in[1];
    const float* w1  = (const float*)d_in[2];
    const float* b1  = (const float*)d_in[3];
    const float* w2  = (const float*)d_in[4];
    const float* b2  = (const float*)d_in[5];
    const float* w3  = (const float*)d_in[6];
    const float* b3  = (const float*)d_in[7];
    const float* fcw = (const float*)d_in[8];
    const float* fcb = (const float*)d_in[9];
    float* out = (float*)d_out;

    char* ws = (char*)d_ws;
    // Workspace (identical footprint to the verified R5 layout, minus probes):
    //  c1p  [0,           57,016,320)  conv1 -> (in-place pack) -> conv2
    //  c2p  [57,016,320,  87,425,024)  conv2 -> (in-place pack) -> conv3
    //  xpad [87,425,024, 107,386,880)  pad  -> conv1        (dead after conv1)
    //  wT1  [107,386,880, 107,397,120) fp32 (conv1)
    //  wT2p [107,397,120, 107,601,920) packed hi/lo (conv2 MFMA)
    //  wT3p [107,601,920, 107,896,832) packed hi/lo (conv3 MFMA)
    //  c3   [0,           51,380,224)  conv3 -> roi      (c1p dead after pack+conv2)
    //  S    [57,016,320, 109,445,120)  roi -> fc         (c2p packed dead)
    //  part [0,           33,554,432)  fc -> reduce      (c3 dead after roi)
    float* c1p  = (float*)(ws);
    float* c2p  = (float*)(ws + 57016320);
    float* xpad = (float*)(ws + 87425024);
    float* wT1  = (float*)(ws + 107386880);
    unsigned* wT2p = (unsigned*)(ws + 107397120);
    unsigned* wT3p = (unsigned*)(ws + 107601920);
    float* c3   = (float*)(ws);
    float* S    = (float*)(ws + 57016320);
    float* part = (float*)(ws);

    wtr_k<32, 75, 80><<<10, 256, 0, stream>>>(w1, wT1);
    wtr_pack_k<64, 800, 800><<<200, 256, 0, stream>>>(w2, wT2p);
    wtr_pack_k<128, 576, 576><<<288, 256, 0, stream>>>(w3, wT3p);
    pad_x_k<<<32 * 3 * 57, 256, 0, stream>>>(x, xpad);
    zb_c1p_k<<<1024, 256, 0, stream>>>(c1p);
    zb_c2p_k<<<2048, 64, 0, stream>>>(c2p);

    // conv1 (fp32): 32co x 128px, 4x4 micro, 256 thr, BK=16, MINW=4
    conv_gemm_k<3, 2, 5, 5, 75, 80, 228, 228, 0, 112, 12544,
                32, 128, 4, 4, 116, 120, 2, 4, 4, 256, 16>
        <<<3136, 256, 0, stream>>>(xpad, wT1, b1, c1p);

    // conv2 (MFMA): in-place pack c1p, then 64co x 100352px, K=800
    split_pack_k<<<4096, 256, 0, stream>>>(c1p, (unsigned*)c1p, 14254080);
    conv_mfma_k<32, 2, 5, 5, 800, 116, 120, 2, 64, 56, 58, 64, 1, 4>
        <<<dim3(49, 1, 32), 256, 0, stream>>>((unsigned*)c1p, wT2p, b2, c2p);

    // conv3 (MFMA): in-place pack c2p, then 128co x 100352px, K=576
    split_pack_k<<<4096, 256, 0, stream>>>(c2p, (unsigned*)c2p, 7602176);
    conv_mfma_k<64, 1, 3, 3, 576, 58, 64, 3, 128, 56, 56, 56, 0, 0>
        <<<dim3(49, 2, 32), 256, 0, stream>>>((unsigned*)c2p, wT3p, b3, c3);

    // ROI sampling -> S[b][c][r][p]
    roi_k<<<1024, 256, 0, stream>>>(c3, ROI, S);
    // FC: split-K 32 + reduce
    fc2_k<<<dim3(2, 8, 32), 256, 0, stream>>>(S, fcw, part);
    fc2_reduce_k<<<1024, 256, 0, stream>>>(part, fcb, out);
}

// Round 8
// 499.028 us; speedup vs baseline: 1.2874x; 1.0520x over previous
//
#include <hip/hip_runtime.h>
#include <hip/hip_bf16.h>

#define LEAK 0.2f

__device__ __forceinline__ float lrelu(float a) { return a > 0.0f ? a : LEAK * a; }

typedef __attribute__((ext_vector_type(8))) short short8;
typedef __attribute__((ext_vector_type(4))) float f32x4;

// bf16 RNE rounding done manually (no dependence on __hip_bfloat16 ABI).
__device__ __forceinline__ unsigned short bf16_hi_bits(float x) {
    unsigned u = __builtin_bit_cast(unsigned, x);
    unsigned r = u + 0x7fffu + ((u >> 16) & 1u);
    return (unsigned short)(r >> 16);
}
__device__ __forceinline__ float bf16_to_f32(unsigned short h) {
    unsigned u = ((unsigned)h) << 16;
    return __builtin_bit_cast(float, u);
}

// v_perm_b32 pair-packers: dwords are packed {hi-bf16 in low16, lo-bf16 in high16}.
// lo16s of (e,o) -> e.lo | o.lo<<16 ; hi16s -> e.hi | o.hi<<16.
__device__ __forceinline__ unsigned pack_lo16(unsigned o, unsigned e) {
    return __builtin_amdgcn_perm(o, e, 0x05040100u);
}
__device__ __forceinline__ unsigned pack_hi16(unsigned o, unsigned e) {
    return __builtin_amdgcn_perm(o, e, 0x07060302u);
}

// ---------------------------------------------------------------------------
// Implicit-GEMM conv + leaky ReLU (fp32 vector path — conv1 only now).
// ---------------------------------------------------------------------------
template<int CI, int ST, int KH, int KW, int KIN, int KP,
         int PIH, int PIW, int LP, int OW, int PPI,
         int CO, int NT, int MR, int NR, int OSH, int OSW, int OR0, int OC0,
         int MINW, int NTHR, int BK>
__global__ __launch_bounds__(NTHR, MINW) void conv_gemm_k(
    const float* __restrict__ in,    // padded input [img*CI + ci][PIH][PIW]
    const float* __restrict__ wT,    // [KP][CO]
    const float* __restrict__ bias,
    float* __restrict__ out)
{
    constexpr int KT  = KP / BK;
    constexpr int TXW = NT / 4;         // B staging pixel-quads per k-row
    constexpr int TXN = NT / NR;        // compute columns
    constexpr int BT  = BK * NT / 4;
    constexpr int AT  = BK * CO / 4;
    constexpr int BI  = (BT + NTHR - 1) / NTHR;
    constexpr int AI  = (AT + NTHR - 1) / NTHR;
    constexpr int ASZ = BK * CO;
    constexpr int BSZ = BK * NT;

    __shared__ float sm[2 * ASZ + 2 * BSZ];

    const int tid = threadIdx.x;
    const int bx  = blockIdx.x;
    const int tx  = tid % TXN;
    const int ty  = tid / TXN;

    // ---- per-thread staging geometry (K-independent) ----
    int bofs[BI], bkl[BI], bcol[BI];
#pragma unroll
    for (int q = 0; q < BI; ++q) {
        int task = tid + q * NTHR;
        if ((BT % NTHR == 0) || task < BT) {
            int kl  = task / TXW;
            int pxq = task % TXW;
            int px0 = bx * NT + pxq * 4;
            int img = px0 / PPI;
            int n   = px0 % PPI;
            int oh  = n / OW, ow = n % OW;
            bofs[q] = ((img * CI) * PIH + oh * ST) * PIW + ow * ST + LP;
            bkl[q]  = kl;
            bcol[q] = (NR == 8) ? (((pxq & 1) * (TXW / 2) + (pxq >> 1)) * 4)
                                : (pxq * 4);
        }
    }

    float  br[BI][4];
    float4 ar[AI];

    auto gather = [&](int it) {
        int k0 = it * BK;
#pragma unroll
        for (int q = 0; q < BI; ++q) {
            int task = tid + q * NTHR;
            if ((BT % NTHR == 0) || task < BT) {
                int k = k0 + bkl[q];
                if (KP > KIN) k = min(k, KIN - 1);   // padded-K tail (weights 0)
                int ci  = k / (KH * KW);
                int rem = k - ci * (KH * KW);
                int kh  = rem / KW;
                int kw  = rem - kh * KW;
                const float* __restrict__ s = in + bofs[q] + (ci * PIH + kh) * PIW + kw;
                br[q][0] = s[0]; br[q][1] = s[ST]; br[q][2] = s[2 * ST]; br[q][3] = s[3 * ST];
            }
        }
#pragma unroll
        for (int p = 0; p < AI; ++p) {
            int task = tid + p * NTHR;
            if ((AT % NTHR == 0) || task < AT)
                ar[p] = *(const float4*)&wT[(size_t)k0 * CO + task * 4];
        }
    };

    float acc[MR][NR];
#pragma unroll
    for (int j = 0; j < MR; ++j) {
        float bv = bias[ty * MR + j];
#pragma unroll
        for (int i = 0; i < NR; ++i) acc[j][i] = bv;
    }

    gather(0);
    for (int it = 0; it < KT; ++it) {
        const int p = it & 1;
        float* __restrict__ Asb = sm + p * ASZ;
        float* __restrict__ Bsb = sm + 2 * ASZ + p * BSZ;
#pragma unroll
        for (int pa = 0; pa < AI; ++pa) {
            int task = tid + pa * NTHR;
            if ((AT % NTHR == 0) || task < AT)
                *(float4*)&Asb[task * 4] = ar[pa];
        }
#pragma unroll
        for (int q = 0; q < BI; ++q) {
            int task = tid + q * NTHR;
            if ((BT % NTHR == 0) || task < BT)
                *(float4*)&Bsb[bkl[q] * NT + bcol[q]] =
                    make_float4(br[q][0], br[q][1], br[q][2], br[q][3]);
        }
        __syncthreads();
        if (it + 1 < KT) gather(it + 1);
#pragma unroll
        for (int k = 0; k < BK; ++k) {
            float b[NR], a[MR];
            if (NR == 8) {
                *(float4*)&b[0] = *(const float4*)&Bsb[k * NT + tx * 4];
                *(float4*)&b[4] = *(const float4*)&Bsb[k * NT + NT / 2 + tx * 4];
            } else {
#pragma unroll
                for (int i = 0; i < NR / 4; ++i)
                    *(float4*)&b[4 * i] = *(const float4*)&Bsb[k * NT + tx * NR + 4 * i];
            }
#pragma unroll
            for (int j = 0; j < MR / 4; ++j)
                *(float4*)&a[4 * j] = *(const float4*)&Asb[k * CO + ty * MR + 4 * j];
#pragma unroll
            for (int j = 0; j < MR; ++j)
#pragma unroll
                for (int i = 0; i < NR; ++i)
                    acc[j][i] += a[j] * b[i];
        }
    }

    {
        int pxs = bx * NT + tx * NR;
        int img = pxs / PPI;
        int n   = pxs % PPI;
        int oh  = n / OW, ow = n % OW;
#pragma unroll
        for (int j = 0; j < MR; ++j) {
            int co = ty * MR + j;
            size_t off = (((size_t)img * CO + co) * OSH + (oh + OR0)) * OSW + (ow + OC0);
#pragma unroll
            for (int q = 0; q < NR / 4; ++q) {
                float4 v = make_float4(lrelu(acc[j][4 * q + 0]), lrelu(acc[j][4 * q + 1]),
                                       lrelu(acc[j][4 * q + 2]), lrelu(acc[j][4 * q + 3]));
                *(float4*)&out[off + 4 * q] = v;
            }
        }
    }
}

// ---------------------------------------------------------------------------
// Weight transpose fp32 (conv1): wT[k][co] = w[co][k], K padded with zeros.
// ---------------------------------------------------------------------------
template<int CO, int KIN, int KP>
__global__ __launch_bounds__(256) void wtr_k(const float* __restrict__ w,
                                             float* __restrict__ wT) {
    int i = blockIdx.x * 256 + threadIdx.x;
    if (i >= KP * CO) return;
    int k = i / CO, co = i % CO;
    wT[i] = (k < KIN) ? w[(size_t)co * KIN + k] : 0.0f;
}

// Weight transpose + bf16 hi/lo pack (conv2/conv3 MFMA path).
template<int CO, int KIN, int KP>
__global__ __launch_bounds__(256) void wtr_pack_k(const float* __restrict__ w,
                                                  unsigned* __restrict__ wTp) {
    int i = blockIdx.x * 256 + threadIdx.x;
    if (i >= KP * CO) return;
    int k = i / CO, co = i % CO;
    float x = (k < KIN) ? w[(size_t)co * KIN + k] : 0.0f;
    unsigned short h = bf16_hi_bits(x);
    float lo = x - bf16_to_f32(h);
    wTp[i] = (unsigned)h | ((unsigned)bf16_hi_bits(lo) << 16);
}

// ---------------------------------------------------------------------------
// In-place pack fp32 -> dword {bf16 hi (low16), bf16 lo (high16)}. x ~= hi+lo.
// Per-element read-then-write at the same index: race-free in place.
// ---------------------------------------------------------------------------
__global__ __launch_bounds__(256) void split_pack_k(const float* __restrict__ src,
                                                    unsigned* __restrict__ dst, int n) {
    for (int i = blockIdx.x * 256 + threadIdx.x; i < n; i += gridDim.x * 256) {
        float x = src[i];
        unsigned short h = bf16_hi_bits(x);
        float lo = x - bf16_to_f32(h);
        unsigned short l = bf16_hi_bits(lo);
        dst[i] = (unsigned)h | ((unsigned)l << 16);
    }
}

// ---------------------------------------------------------------------------
// Conv as bf16 hi/lo split-GEMM on MFMA (conv2 and conv3) — v2.
// VALU-diet vs R6 (which measured VALUBusy 68% / MfmaUtil 18%):
//  * per-block LDS offset table kills the per-element k->(ci,kh,kw) division
//    chain (offsets are wave-uniform; loaded via broadcast int4 ds_reads)
//  * v_perm_b32 pair-packing halves the hi/lo unpack cost
//  * A-gather through one hoisted base + j*CO immediate offsets
// Structure (tile/frag/LDS layout, proven R6): 64co x 64px, 4 waves,
// each wave 32co x 32px = 2x2 16x16 frags; BK=32; double-buffered LDS;
// rows padded to 40 shorts (80B); products HH+HL+LH.
// ---------------------------------------------------------------------------
template<int CI, int ST, int KH, int KW, int KP,
         int PIH, int PIW, int LP,
         int CO, int OW, int OSH, int OSW, int OR0, int OC0>
__global__ __launch_bounds__(256, 2) void conv_mfma_k(
    const unsigned* __restrict__ src,   // packed act [img*CI+ci][PIH][PIW]
    const unsigned* __restrict__ wp,    // packed wT  [KP][CO]
    const float* __restrict__ bias,
    float* __restrict__ outp)
{
    constexpr int KT = KP / 32;
    __shared__ unsigned ldsu[10240];    // 2 buf x 4 arrays x 64 rows x 20 dw
    __shared__ int offtab[KP];
    short* const lds = (short*)ldsu;

    const int tid  = threadIdx.x;
    const int lane = tid & 63;
    const int wv   = tid >> 6;          // wave 0..3
    const int bx   = blockIdx.x;        // 49 px tiles
    const int by   = blockIdx.y;        // CO/64 co tiles
    const int bz   = blockIdx.z;        // 32 imgs

    // one-time k -> activation-offset table (amortizes the division chain)
    for (int k = tid; k < KP; k += 256) {
        int ci = k / (KH * KW), r = k - ci * (KH * KW);
        int kh = r / KW, kw = r - kh * KW;
        offtab[k] = (ci * PIH + kh) * PIW + kw;
    }
    __syncthreads();

    const int row = lane;               // staging row; k-slot = wave (8 k each)
    const int n   = bx * 64 + row;      // 0..3135
    const int oh  = n / OW, ow = n % OW;
    const unsigned* __restrict__ bsrc =
        src + ((size_t)(bz * CI) * PIH + oh * ST) * PIW + ow * ST + LP;
    const unsigned* __restrict__ wsrc = wp + (size_t)(wv * 8) * CO + by * 64 + row;

    unsigned Au[8], Bu[8];
    auto gather = [&](int it) {
        const int k0 = it * 32 + wv * 8;
        int4 o0 = *(const int4*)&offtab[k0];       // broadcast ds_read
        int4 o1 = *(const int4*)&offtab[k0 + 4];
        const unsigned* __restrict__ wk = wsrc + (size_t)it * 32 * CO;
#pragma unroll
        for (int j = 0; j < 8; ++j) Au[j] = wk[j * CO];
        Bu[0] = bsrc[o0.x]; Bu[1] = bsrc[o0.y]; Bu[2] = bsrc[o0.z]; Bu[3] = bsrc[o0.w];
        Bu[4] = bsrc[o1.x]; Bu[5] = bsrc[o1.y]; Bu[6] = bsrc[o1.z]; Bu[7] = bsrc[o1.w];
    };

    f32x4 acc[2][2] = {};

    const int cw = wv & 1, pw = wv >> 1;
    const int r15 = lane & 15, kg = lane >> 4;

    gather(0);
    for (int it = 0; it < KT; ++it) {
        const int p = it & 1;
        {
            const int widx = row * 20 + wv * 4;    // dword index within array
            uint4 vh, vl;
            vh.x = pack_lo16(Au[1], Au[0]); vl.x = pack_hi16(Au[1], Au[0]);
            vh.y = pack_lo16(Au[3], Au[2]); vl.y = pack_hi16(Au[3], Au[2]);
            vh.z = pack_lo16(Au[5], Au[4]); vl.z = pack_hi16(Au[5], Au[4]);
            vh.w = pack_lo16(Au[7], Au[6]); vl.w = pack_hi16(Au[7], Au[6]);
            *(uint4*)&ldsu[(p * 4 + 0) * 1280 + widx] = vh;
            *(uint4*)&ldsu[(p * 4 + 1) * 1280 + widx] = vl;
            vh.x = pack_lo16(Bu[1], Bu[0]); vl.x = pack_hi16(Bu[1], Bu[0]);
            vh.y = pack_lo16(Bu[3], Bu[2]); vl.y = pack_hi16(Bu[3], Bu[2]);
            vh.z = pack_lo16(Bu[5], Bu[4]); vl.z = pack_hi16(Bu[5], Bu[4]);
            vh.w = pack_lo16(Bu[7], Bu[6]); vl.w = pack_hi16(Bu[7], Bu[6]);
            *(uint4*)&ldsu[(p * 4 + 2) * 1280 + widx] = vh;
            *(uint4*)&ldsu[(p * 4 + 3) * 1280 + widx] = vl;
        }
        __syncthreads();
        if (it + 1 < KT) gather(it + 1);

        const short* AsH = lds + (p * 4 + 0) * 2560;
        const short* AsL = lds + (p * 4 + 1) * 2560;
        const short* BsH = lds + (p * 4 + 2) * 2560;
        const short* BsL = lds + (p * 4 + 3) * 2560;
        short8 aH[2], aL[2], bH[2], bL[2];
#pragma unroll
        for (int tq = 0; tq < 2; ++tq) {
            const int ra = (cw * 32 + tq * 16 + r15) * 40 + kg * 8;
            aH[tq] = *(const short8*)&AsH[ra];
            aL[tq] = *(const short8*)&AsL[ra];
            const int rb = (pw * 32 + tq * 16 + r15) * 40 + kg * 8;
            bH[tq] = *(const short8*)&BsH[rb];
            bL[tq] = *(const short8*)&BsL[rb];
        }
#pragma unroll
        for (int ct = 0; ct < 2; ++ct)
#pragma unroll
            for (int pt = 0; pt < 2; ++pt) {
                acc[ct][pt] = __builtin_amdgcn_mfma_f32_16x16x32_bf16(aH[ct], bH[pt], acc[ct][pt], 0, 0, 0);
                acc[ct][pt] = __builtin_amdgcn_mfma_f32_16x16x32_bf16(aH[ct], bL[pt], acc[ct][pt], 0, 0, 0);
                acc[ct][pt] = __builtin_amdgcn_mfma_f32_16x16x32_bf16(aL[ct], bH[pt], acc[ct][pt], 0, 0, 0);
            }
    }

    // C/D: col = lane&15 -> px, row = (lane>>4)*4+reg -> co
#pragma unroll
    for (int ct = 0; ct < 2; ++ct)
#pragma unroll
        for (int pt = 0; pt < 2; ++pt)
#pragma unroll
            for (int rg = 0; rg < 4; ++rg) {
                int co = by * 64 + cw * 32 + ct * 16 + kg * 4 + rg;
                int px = bx * 64 + pw * 32 + pt * 16 + r15;
                int poh = px / OW, pow_ = px % OW;
                float v = acc[ct][pt][rg] + bias[co];
                outp[((size_t)(bz * CO + co) * OSH + (poh + OR0)) * OSW + (pow_ + OC0)] = lrelu(v);
            }
}

// ---------------------------------------------------------------------------
// x -> x_pad [32*3][228][228], 2-pixel zero border.
// ---------------------------------------------------------------------------
__global__ __launch_bounds__(256) void pad_x_k(const float* __restrict__ x,
                                               float* __restrict__ xp) {
    int blk = blockIdx.x;              // 32*3*57
    int r4 = blk % 57, ic = blk / 57;
    int wid = threadIdx.x >> 6, lane = threadIdx.x & 63;
    int row = r4 * 4 + wid;
    const float* __restrict__ src = x + (size_t)ic * 224 * 224 + (size_t)(row - 2) * 224;
    float* __restrict__ dst = xp + (size_t)ic * 228 * 228 + (size_t)row * 228;
    bool rok = (row >= 2) && (row < 226);
    for (int c = lane; c < 228; c += 64) {
        float v = 0.0f;
        if (rok && c >= 2 && c < 226) v = src[c - 2];
        dst[c] = v;
    }
}

// c1p plane = 116 x 120; data ow at layout col ow+4 (border cols 2,3,116,117).
__global__ __launch_bounds__(256) void zb_c1p_k(float* __restrict__ p) {
    float* base = p + (size_t)blockIdx.x * (116 * 120);
    for (int t = threadIdx.x; t < 928; t += 256) {
        int idx;
        if (t < 480) {
            int r = t / 120, c = t - r * 120;
            int row = (r < 2) ? r : r + 112;
            idx = row * 120 + c;
        } else {
            int s = t - 480;
            int r = s >> 2, c = s & 3;
            int col = (c < 2) ? (c + 2) : (c + 114);
            idx = (r + 2) * 120 + col;
        }
        base[idx] = 0.0f;
    }
}

// c2p plane = 58 x 64; data ow at layout col ow+4 (border cols 3,60).
__global__ __launch_bounds__(64) void zb_c2p_k(float* __restrict__ p) {
    float* base = p + (size_t)blockIdx.x * (58 * 64);
    for (int t = threadIdx.x; t < 240; t += 64) {
        int idx;
        if (t < 128) {
            int r = t >> 6, c = t & 63;
            idx = (r ? 57 : 0) * 64 + c;
        } else {
            int s = t - 128;
            int r = (s >> 1) + 1;
            idx = r * 64 + ((s & 1) ? 60 : 3);
        }
        base[idx] = 0.0f;
    }
}

// ---------------------------------------------------------------------------
// ROI bilinear sampling (unchanged). S[b][c][r][p] == reference reshape quirk.
// ---------------------------------------------------------------------------
__global__ __launch_bounds__(256) void roi_k(const float* __restrict__ feat,
                                             const float* __restrict__ roi,
                                             float* __restrict__ S) {
    int b = blockIdx.x >> 5;
    int r = blockIdx.x & 31;
    const float* rr = roi + (size_t)(b * 32 + r) * 7;

    __shared__ int   offA[100], offB[100], offC[100], offD[100];
    __shared__ float wA[100], wB[100], wC[100], wD[100];

    int tid = threadIdx.x;
    if (tid < 100) {
        int i = tid / 10, j = tid % 10;
        float cx = rr[0], cy = rr[1];
        float W1 = rr[2], W2 = rr[3], H1 = rr[4], H2 = rr[5], psi = rr[6];
        float offx = ((float)j - 4.5f) / 10.0f;
        float offy = ((float)i - 4.5f) / 10.0f;
        float gx = offx * (W1 + W2) - (W1 - W2) * 0.5f;
        float gy = offy * (H1 + H2) - (H1 - H2) * 0.5f;
        float sn = sinf(psi), cs = cosf(psi);
        float xs = gx * cs + gy * sn + cx;
        float ys = -gx * sn + gy * cs + cy;

        float x0f = floorf(xs), y0f = floorf(ys);
        int x0 = (int)x0f, x1 = x0 + 1;
        int y0 = (int)y0f, y1 = y0 + 1;
        x0 = min(max(x0, 0), 55); x1 = min(max(x1, 0), 55);
        y0 = min(max(y0, 0), 55); y1 = min(max(y1, 0), 55);
        float fx0 = (float)x0, fx1 = (float)x1;
        float fy0 = (float)y0, fy1 = (float)y1;
        float step = (fx1 - fx0) * (fy1 - fy0);
        step = fminf(fmaxf(step, 0.001f), 2.0f);
        float inv = 1.0f / step;
        wA[tid] = (fx1 - xs) * (fy1 - ys) * inv;
        wB[tid] = (fx1 - xs) * (ys - fy0) * inv;
        wC[tid] = (xs - fx0) * (fy1 - ys) * inv;
        wD[tid] = (xs - fx0) * (ys - fy0) * inv;
        offA[tid] = y0 * 56 + x0;
        offB[tid] = y1 * 56 + x0;
        offC[tid] = y0 * 56 + x1;
        offD[tid] = y1 * 56 + x1;
    }
    __syncthreads();

    const float* __restrict__ fb = feat + (size_t)b * 128 * 3136;
    float* __restrict__ outb = S + ((size_t)b * 128 * 32 + r) * 100;
    int c = tid / 100;
    int p = tid - c * 100;
    for (int t = tid; t < 12800; t += 256) {
        const float* f = fb + c * 3136;
        float v = wA[p] * f[offA[p]] + wB[p] * f[offB[p]] +
                  wC[p] * f[offC[p]] + wD[p] * f[offD[p]];
        outb[(size_t)c * 3200 + p] = v;
        p += 56; c += 2;
        if (p >= 100) { p -= 100; ++c; }
    }
}

// ---------------------------------------------------------------------------
// FC split-K GEMM v6: 128x128 tile, 8x8 micro, BK=16, ksplit=32.
// ---------------------------------------------------------------------------
__global__ __launch_bounds__(256, 2) void fc2_k(const float* __restrict__ A,
                                                const float* __restrict__ B,
                                                float* __restrict__ part) {
    constexpr int PAD = 132;
    __shared__ float sm[2 * 2 * 16 * PAD];

    const int tid = threadIdx.x;
    const int bn = blockIdx.x, bm = blockIdx.y, ks = blockIdx.z;
    const int tx = tid & 15, ty = tid >> 4;
    const int m0 = tid >> 2;
    const int kq = tid & 3;

    const int pc0 = (((m0 >> 2) & 1) * 16 + (m0 >> 3)) * 4 + (m0 & 3);

    const float* __restrict__ a0 = A + (size_t)(bm * 128 + m0) * 12800 + ks * 400 + kq * 4;
    const float* __restrict__ a1 = a0 + (size_t)64 * 12800;
    const float* __restrict__ b0 = B + (size_t)(bn * 128 + m0) * 12800 + ks * 400 + kq * 4;
    const float* __restrict__ b1 = b0 + (size_t)64 * 12800;

    float4 ar0 = *(const float4*)a0;
    float4 ar1 = *(const float4*)a1;
    float4 br0 = *(const float4*)b0;
    float4 br1 = *(const float4*)b1;

    float acc[8][8] = {};

    for (int it = 0; it < 25; ++it) {
        const int p = it & 1;
        float* __restrict__ As = sm + p * (2 * 16 * PAD);
        float* __restrict__ Ws = As + 16 * PAD;
        const int base = kq * 4 * PAD + pc0;
        As[base]                = ar0.x; As[base + PAD]          = ar0.y;
        As[base + 2 * PAD]      = ar0.z; As[base + 3 * PAD]      = ar0.w;
        As[base + 32]           = ar1.x; As[base + 32 + PAD]     = ar1.y;
        As[base + 32 + 2 * PAD] = ar1.z; As[base + 32 + 3 * PAD] = ar1.w;
        Ws[base]                = br0.x; Ws[base + PAD]          = br0.y;
        Ws[base + 2 * PAD]      = br0.z; Ws[base + 3 * PAD]      = br0.w;
        Ws[base + 32]           = br1.x; Ws[base + 32 + PAD]     = br1.y;
        Ws[base + 32 + 2 * PAD] = br1.z; Ws[base + 32 + 3 * PAD] = br1.w;
        __syncthreads();
        if (it + 1 < 25) {
            ar0 = *(const float4*)(a0 + (it + 1) * 16);
            ar1 = *(const float4*)(a1 + (it + 1) * 16);
            br0 = *(const float4*)(b0 + (it + 1) * 16);
            br1 = *(const float4*)(b1 + (it + 1) * 16);
        }
#pragma unroll
        for (int k = 0; k < 16; ++k) {
            float4 aL = *(const float4*)&As[k * PAD + ty * 4];
            float4 aH = *(const float4*)&As[k * PAD + 64 + ty * 4];
            float4 bL = *(const float4*)&Ws[k * PAD + tx * 4];
            float4 bH = *(const float4*)&Ws[k * PAD + 64 + tx * 4];
            float a[8] = {aL.x, aL.y, aL.z, aL.w, aH.x, aH.y, aH.z, aH.w};
            float b[8] = {bL.x, bL.y, bL.z, bL.w, bH.x, bH.y, bH.z, bH.w};
#pragma unroll
            for (int j = 0; j < 8; ++j)
#pragma unroll
                for (int i = 0; i < 8; ++i)
                    acc[j][i] += a[j] * b[i];
        }
    }

    float* __restrict__ po = part + (size_t)ks * 262144
                                  + (size_t)(bm * 128 + ty * 8) * 256 + bn * 128 + tx * 8;
#pragma unroll
    for (int j = 0; j < 8; ++j) {
        *(float4*)(po + (size_t)j * 256)     = make_float4(acc[j][0], acc[j][1], acc[j][2], acc[j][3]);
        *(float4*)(po + (size_t)j * 256 + 4) = make_float4(acc[j][4], acc[j][5], acc[j][6], acc[j][7]);
    }
}

__global__ __launch_bounds__(256) void fc2_reduce_k(const float* __restrict__ part,
                                                    const float* __restrict__ bias,
                                                    float* __restrict__ out) {
    int i = blockIdx.x * 256 + threadIdx.x;   // 0..262143
    float s = bias[i & 255];
    for (int ks = 0; ks < 32; ++ks) s += part[(size_t)ks * 262144 + i];
    out[i] = s;
}

// ---------------------------------------------------------------------------
extern "C" void kernel_launch(void* const* d_in, const int* in_sizes, int n_in,
                              void* d_out, int out_size, void* d_ws, size_t ws_size,
                              hipStream_t stream) {
    const float* x   = (const float*)d_in[0];
    const float* ROI = (const float*)d_in[1];
    const float* w1  = (const float*)d_in[2];
    const float* b1  = (const float*)d_in[3];
    const float* w2  = (const float*)d_in[4];
    const float* b2  = (const float*)d_in[5];
    const float* w3  = (const float*)d_in[6];
    const float* b3  = (const float*)d_in[7];
    const float* fcw = (const float*)d_in[8];
    const float* fcb = (const float*)d_in[9];
    float* out = (float*)d_out;

    char* ws = (char*)d_ws;
    // Workspace (identical to verified R6 layout):
    //  c1p  [0,           57,016,320)  conv1 -> (in-place pack) -> conv2
    //  c2p  [57,016,320,  87,425,024)  conv2 -> (in-place pack) -> conv3
    //  xpad [87,425,024, 107,386,880)  pad  -> conv1        (dead after conv1)
    //  wT1  [107,386,880, 107,397,120) fp32 (conv1)
    //  wT2p [107,397,120, 107,601,920) packed hi/lo (conv2 MFMA)
    //  wT3p [107,601,920, 107,896,832) packed hi/lo (conv3 MFMA)
    //  c3   [0,           51,380,224)  conv3 -> roi      (c1p dead after pack+conv2)
    //  S    [57,016,320, 109,445,120)  roi -> fc         (c2p packed dead)
    //  part [0,           33,554,432)  fc -> reduce      (c3 dead after roi)
    float* c1p  = (float*)(ws);
    float* c2p  = (float*)(ws + 57016320);
    float* xpad = (float*)(ws + 87425024);
    float* wT1  = (float*)(ws + 107386880);
    unsigned* wT2p = (unsigned*)(ws + 107397120);
    unsigned* wT3p = (unsigned*)(ws + 107601920);
    float* c3   = (float*)(ws);
    float* S    = (float*)(ws + 57016320);
    float* part = (float*)(ws);

    wtr_k<32, 75, 80><<<10, 256, 0, stream>>>(w1, wT1);
    wtr_pack_k<64, 800, 800><<<200, 256, 0, stream>>>(w2, wT2p);
    wtr_pack_k<128, 576, 576><<<288, 256, 0, stream>>>(w3, wT3p);
    pad_x_k<<<32 * 3 * 57, 256, 0, stream>>>(x, xpad);
    zb_c1p_k<<<1024, 256, 0, stream>>>(c1p);
    zb_c2p_k<<<2048, 64, 0, stream>>>(c2p);

    // conv1 (fp32): 32co x 128px, 4x4 micro, 256 thr, BK=16, MINW=4
    conv_gemm_k<3, 2, 5, 5, 75, 80, 228, 228, 0, 112, 12544,
                32, 128, 4, 4, 116, 120, 2, 4, 4, 256, 16>
        <<<3136, 256, 0, stream>>>(xpad, wT1, b1, c1p);

    // conv2 (MFMA): in-place pack c1p, then 64co x 100352px, K=800
    split_pack_k<<<4096, 256, 0, stream>>>(c1p, (unsigned*)c1p, 14254080);
    conv_mfma_k<32, 2, 5, 5, 800, 116, 120, 2, 64, 56, 58, 64, 1, 4>
        <<<dim3(49, 1, 32), 256, 0, stream>>>((unsigned*)c1p, wT2p, b2, c2p);

    // conv3 (MFMA): in-place pack c2p, then 128co x 100352px, K=576
    split_pack_k<<<4096, 256, 0, stream>>>(c2p, (unsigned*)c2p, 7602176);
    conv_mfma_k<64, 1, 3, 3, 576, 58, 64, 3, 128, 56, 56, 56, 0, 0>
        <<<dim3(49, 2, 32), 256, 0, stream>>>((unsigned*)c2p, wT3p, b3, c3);

    // ROI sampling -> S[b][c][r][p]
    roi_k<<<1024, 256, 0, stream>>>(c3, ROI, S);
    // FC: split-K 32 + reduce
    fc2_k<<<dim3(2, 8, 32), 256, 0, stream>>>(S, fcw, part);
    fc2_reduce_k<<<1024, 256, 0, stream>>>(part, fcb, out);
}

// Round 9
// 457.192 us; speedup vs baseline: 1.4052x; 1.0915x over previous
//
#include <hip/hip_runtime.h>
#include <hip/hip_bf16.h>

#define LEAK 0.2f

__device__ __forceinline__ float lrelu(float a) { return a > 0.0f ? a : LEAK * a; }

typedef __attribute__((ext_vector_type(8))) short short8;
typedef __attribute__((ext_vector_type(4))) float f32x4;

// bf16 RNE rounding done manually (no dependence on __hip_bfloat16 ABI).
__device__ __forceinline__ unsigned short bf16_hi_bits(float x) {
    unsigned u = __builtin_bit_cast(unsigned, x);
    unsigned r = u + 0x7fffu + ((u >> 16) & 1u);
    return (unsigned short)(r >> 16);
}
__device__ __forceinline__ float bf16_to_f32(unsigned short h) {
    unsigned u = ((unsigned)h) << 16;
    return __builtin_bit_cast(float, u);
}
__device__ __forceinline__ unsigned pack_bf16pair(float x) {
    unsigned short h = bf16_hi_bits(x);
    float lo = x - bf16_to_f32(h);
    return (unsigned)h | ((unsigned)bf16_hi_bits(lo) << 16);
}

// v_perm_b32 pair-packers: dwords are packed {hi-bf16 in low16, lo-bf16 in high16}.
__device__ __forceinline__ unsigned pack_lo16(unsigned o, unsigned e) {
    return __builtin_amdgcn_perm(o, e, 0x05040100u);
}
__device__ __forceinline__ unsigned pack_hi16(unsigned o, unsigned e) {
    return __builtin_amdgcn_perm(o, e, 0x07060302u);
}

// ---------------------------------------------------------------------------
// Implicit-GEMM conv + leaky ReLU (fp32 vector path — conv1 only now).
// ---------------------------------------------------------------------------
template<int CI, int ST, int KH, int KW, int KIN, int KP,
         int PIH, int PIW, int LP, int OW, int PPI,
         int CO, int NT, int MR, int NR, int OSH, int OSW, int OR0, int OC0,
         int MINW, int NTHR, int BK>
__global__ __launch_bounds__(NTHR, MINW) void conv_gemm_k(
    const float* __restrict__ in,    // padded input [img*CI + ci][PIH][PIW]
    const float* __restrict__ wT,    // [KP][CO]
    const float* __restrict__ bias,
    float* __restrict__ out)
{
    constexpr int KT  = KP / BK;
    constexpr int TXW = NT / 4;         // B staging pixel-quads per k-row
    constexpr int TXN = NT / NR;        // compute columns
    constexpr int BT  = BK * NT / 4;
    constexpr int AT  = BK * CO / 4;
    constexpr int BI  = (BT + NTHR - 1) / NTHR;
    constexpr int AI  = (AT + NTHR - 1) / NTHR;
    constexpr int ASZ = BK * CO;
    constexpr int BSZ = BK * NT;

    __shared__ float sm[2 * ASZ + 2 * BSZ];

    const int tid = threadIdx.x;
    const int bx  = blockIdx.x;
    const int tx  = tid % TXN;
    const int ty  = tid / TXN;

    // ---- per-thread staging geometry (K-independent) ----
    int bofs[BI], bkl[BI], bcol[BI];
#pragma unroll
    for (int q = 0; q < BI; ++q) {
        int task = tid + q * NTHR;
        if ((BT % NTHR == 0) || task < BT) {
            int kl  = task / TXW;
            int pxq = task % TXW;
            int px0 = bx * NT + pxq * 4;
            int img = px0 / PPI;
            int n   = px0 % PPI;
            int oh  = n / OW, ow = n % OW;
            bofs[q] = ((img * CI) * PIH + oh * ST) * PIW + ow * ST + LP;
            bkl[q]  = kl;
            bcol[q] = (NR == 8) ? (((pxq & 1) * (TXW / 2) + (pxq >> 1)) * 4)
                                : (pxq * 4);
        }
    }

    float  br[BI][4];
    float4 ar[AI];

    auto gather = [&](int it) {
        int k0 = it * BK;
#pragma unroll
        for (int q = 0; q < BI; ++q) {
            int task = tid + q * NTHR;
            if ((BT % NTHR == 0) || task < BT) {
                int k = k0 + bkl[q];
                if (KP > KIN) k = min(k, KIN - 1);   // padded-K tail (weights 0)
                int ci  = k / (KH * KW);
                int rem = k - ci * (KH * KW);
                int kh  = rem / KW;
                int kw  = rem - kh * KW;
                const float* __restrict__ s = in + bofs[q] + (ci * PIH + kh) * PIW + kw;
                br[q][0] = s[0]; br[q][1] = s[ST]; br[q][2] = s[2 * ST]; br[q][3] = s[3 * ST];
            }
        }
#pragma unroll
        for (int p = 0; p < AI; ++p) {
            int task = tid + p * NTHR;
            if ((AT % NTHR == 0) || task < AT)
                ar[p] = *(const float4*)&wT[(size_t)k0 * CO + task * 4];
        }
    };

    float acc[MR][NR];
#pragma unroll
    for (int j = 0; j < MR; ++j) {
        float bv = bias[ty * MR + j];
#pragma unroll
        for (int i = 0; i < NR; ++i) acc[j][i] = bv;
    }

    gather(0);
    for (int it = 0; it < KT; ++it) {
        const int p = it & 1;
        float* __restrict__ Asb = sm + p * ASZ;
        float* __restrict__ Bsb = sm + 2 * ASZ + p * BSZ;
#pragma unroll
        for (int pa = 0; pa < AI; ++pa) {
            int task = tid + pa * NTHR;
            if ((AT % NTHR == 0) || task < AT)
                *(float4*)&Asb[task * 4] = ar[pa];
        }
#pragma unroll
        for (int q = 0; q < BI; ++q) {
            int task = tid + q * NTHR;
            if ((BT % NTHR == 0) || task < BT)
                *(float4*)&Bsb[bkl[q] * NT + bcol[q]] =
                    make_float4(br[q][0], br[q][1], br[q][2], br[q][3]);
        }
        __syncthreads();
        if (it + 1 < KT) gather(it + 1);
#pragma unroll
        for (int k = 0; k < BK; ++k) {
            float b[NR], a[MR];
            if (NR == 8) {
                *(float4*)&b[0] = *(const float4*)&Bsb[k * NT + tx * 4];
                *(float4*)&b[4] = *(const float4*)&Bsb[k * NT + NT / 2 + tx * 4];
            } else {
#pragma unroll
                for (int i = 0; i < NR / 4; ++i)
                    *(float4*)&b[4 * i] = *(const float4*)&Bsb[k * NT + tx * NR + 4 * i];
            }
#pragma unroll
            for (int j = 0; j < MR / 4; ++j)
                *(float4*)&a[4 * j] = *(const float4*)&Asb[k * CO + ty * MR + 4 * j];
#pragma unroll
            for (int j = 0; j < MR; ++j)
#pragma unroll
                for (int i = 0; i < NR; ++i)
                    acc[j][i] += a[j] * b[i];
        }
    }

    {
        int pxs = bx * NT + tx * NR;
        int img = pxs / PPI;
        int n   = pxs % PPI;
        int oh  = n / OW, ow = n % OW;
#pragma unroll
        for (int j = 0; j < MR; ++j) {
            int co = ty * MR + j;
            size_t off = (((size_t)img * CO + co) * OSH + (oh + OR0)) * OSW + (ow + OC0);
#pragma unroll
            for (int q = 0; q < NR / 4; ++q) {
                float4 v = make_float4(lrelu(acc[j][4 * q + 0]), lrelu(acc[j][4 * q + 1]),
                                       lrelu(acc[j][4 * q + 2]), lrelu(acc[j][4 * q + 3]));
                *(float4*)&out[off + 4 * q] = v;
            }
        }
    }
}

// ---------------------------------------------------------------------------
// Weight transpose fp32 (conv1): wT[k][co] = w[co][k], K padded with zeros.
// ---------------------------------------------------------------------------
template<int CO, int KIN, int KP>
__global__ __launch_bounds__(256) void wtr_k(const float* __restrict__ w,
                                             float* __restrict__ wT) {
    int i = blockIdx.x * 256 + threadIdx.x;
    if (i >= KP * CO) return;
    int k = i / CO, co = i % CO;
    wT[i] = (k < KIN) ? w[(size_t)co * KIN + k] : 0.0f;
}

// Weight transpose + bf16 hi/lo pack (conv2/conv3 MFMA path).
template<int CO, int KIN, int KP>
__global__ __launch_bounds__(256) void wtr_pack_k(const float* __restrict__ w,
                                                  unsigned* __restrict__ wTp) {
    int i = blockIdx.x * 256 + threadIdx.x;
    if (i >= KP * CO) return;
    int k = i / CO, co = i % CO;
    float x = (k < KIN) ? w[(size_t)co * KIN + k] : 0.0f;
    wTp[i] = pack_bf16pair(x);
}

// ---------------------------------------------------------------------------
// Pack fp32 -> dword {bf16 hi, bf16 lo}. In-place safe (same-index RMW).
// ---------------------------------------------------------------------------
__global__ __launch_bounds__(256) void split_pack_k(const float* __restrict__ src,
                                                    unsigned* __restrict__ dst, int n) {
    for (int i = blockIdx.x * 256 + threadIdx.x; i < n; i += gridDim.x * 256) {
        dst[i] = pack_bf16pair(src[i]);
    }
}

// ---------------------------------------------------------------------------
// Conv as bf16 hi/lo split-GEMM on MFMA (conv2 and conv3) — v2 (R8-verified:
// conv2 ~? / conv3 ~?; structure proven). 64co x 64px, 4 waves, BK=32,
// LDS offset table, v_perm pair-pack, 40-short padded rows, HH+HL+LH.
// ---------------------------------------------------------------------------
template<int CI, int ST, int KH, int KW, int KP,
         int PIH, int PIW, int LP,
         int CO, int OW, int OSH, int OSW, int OR0, int OC0>
__global__ __launch_bounds__(256, 2) void conv_mfma_k(
    const unsigned* __restrict__ src,   // packed act [img*CI+ci][PIH][PIW]
    const unsigned* __restrict__ wp,    // packed wT  [KP][CO]
    const float* __restrict__ bias,
    float* __restrict__ outp)
{
    constexpr int KT = KP / 32;
    __shared__ unsigned ldsu[10240];    // 2 buf x 4 arrays x 64 rows x 20 dw
    __shared__ int offtab[KP];
    short* const lds = (short*)ldsu;

    const int tid  = threadIdx.x;
    const int lane = tid & 63;
    const int wv   = tid >> 6;          // wave 0..3
    const int bx   = blockIdx.x;        // 49 px tiles
    const int by   = blockIdx.y;        // CO/64 co tiles
    const int bz   = blockIdx.z;        // 32 imgs

    for (int k = tid; k < KP; k += 256) {
        int ci = k / (KH * KW), r = k - ci * (KH * KW);
        int kh = r / KW, kw = r - kh * KW;
        offtab[k] = (ci * PIH + kh) * PIW + kw;
    }
    __syncthreads();

    const int row = lane;               // staging row; k-slot = wave (8 k each)
    const int n   = bx * 64 + row;      // 0..3135
    const int oh  = n / OW, ow = n % OW;
    const unsigned* __restrict__ bsrc =
        src + ((size_t)(bz * CI) * PIH + oh * ST) * PIW + ow * ST + LP;
    const unsigned* __restrict__ wsrc = wp + (size_t)(wv * 8) * CO + by * 64 + row;

    unsigned Au[8], Bu[8];
    auto gather = [&](int it) {
        const int k0 = it * 32 + wv * 8;
        int4 o0 = *(const int4*)&offtab[k0];       // broadcast ds_read
        int4 o1 = *(const int4*)&offtab[k0 + 4];
        const unsigned* __restrict__ wk = wsrc + (size_t)it * 32 * CO;
#pragma unroll
        for (int j = 0; j < 8; ++j) Au[j] = wk[j * CO];
        Bu[0] = bsrc[o0.x]; Bu[1] = bsrc[o0.y]; Bu[2] = bsrc[o0.z]; Bu[3] = bsrc[o0.w];
        Bu[4] = bsrc[o1.x]; Bu[5] = bsrc[o1.y]; Bu[6] = bsrc[o1.z]; Bu[7] = bsrc[o1.w];
    };

    f32x4 acc[2][2] = {};

    const int cw = wv & 1, pw = wv >> 1;
    const int r15 = lane & 15, kg = lane >> 4;

    gather(0);
    for (int it = 0; it < KT; ++it) {
        const int p = it & 1;
        {
            const int widx = row * 20 + wv * 4;    // dword index within array
            uint4 vh, vl;
            vh.x = pack_lo16(Au[1], Au[0]); vl.x = pack_hi16(Au[1], Au[0]);
            vh.y = pack_lo16(Au[3], Au[2]); vl.y = pack_hi16(Au[3], Au[2]);
            vh.z = pack_lo16(Au[5], Au[4]); vl.z = pack_hi16(Au[5], Au[4]);
            vh.w = pack_lo16(Au[7], Au[6]); vl.w = pack_hi16(Au[7], Au[6]);
            *(uint4*)&ldsu[(p * 4 + 0) * 1280 + widx] = vh;
            *(uint4*)&ldsu[(p * 4 + 1) * 1280 + widx] = vl;
            vh.x = pack_lo16(Bu[1], Bu[0]); vl.x = pack_hi16(Bu[1], Bu[0]);
            vh.y = pack_lo16(Bu[3], Bu[2]); vl.y = pack_hi16(Bu[3], Bu[2]);
            vh.z = pack_lo16(Bu[5], Bu[4]); vl.z = pack_hi16(Bu[5], Bu[4]);
            vh.w = pack_lo16(Bu[7], Bu[6]); vl.w = pack_hi16(Bu[7], Bu[6]);
            *(uint4*)&ldsu[(p * 4 + 2) * 1280 + widx] = vh;
            *(uint4*)&ldsu[(p * 4 + 3) * 1280 + widx] = vl;
        }
        __syncthreads();
        if (it + 1 < KT) gather(it + 1);

        const short* AsH = lds + (p * 4 + 0) * 2560;
        const short* AsL = lds + (p * 4 + 1) * 2560;
        const short* BsH = lds + (p * 4 + 2) * 2560;
        const short* BsL = lds + (p * 4 + 3) * 2560;
        short8 aH[2], aL[2], bH[2], bL[2];
#pragma unroll
        for (int tq = 0; tq < 2; ++tq) {
            const int ra = (cw * 32 + tq * 16 + r15) * 40 + kg * 8;
            aH[tq] = *(const short8*)&AsH[ra];
            aL[tq] = *(const short8*)&AsL[ra];
            const int rb = (pw * 32 + tq * 16 + r15) * 40 + kg * 8;
            bH[tq] = *(const short8*)&BsH[rb];
            bL[tq] = *(const short8*)&BsL[rb];
        }
#pragma unroll
        for (int ct = 0; ct < 2; ++ct)
#pragma unroll
            for (int pt = 0; pt < 2; ++pt) {
                acc[ct][pt] = __builtin_amdgcn_mfma_f32_16x16x32_bf16(aH[ct], bH[pt], acc[ct][pt], 0, 0, 0);
                acc[ct][pt] = __builtin_amdgcn_mfma_f32_16x16x32_bf16(aH[ct], bL[pt], acc[ct][pt], 0, 0, 0);
                acc[ct][pt] = __builtin_amdgcn_mfma_f32_16x16x32_bf16(aL[ct], bH[pt], acc[ct][pt], 0, 0, 0);
            }
    }

    // C/D: col = lane&15 -> px, row = (lane>>4)*4+reg -> co
#pragma unroll
    for (int ct = 0; ct < 2; ++ct)
#pragma unroll
        for (int pt = 0; pt < 2; ++pt)
#pragma unroll
            for (int rg = 0; rg < 4; ++rg) {
                int co = by * 64 + cw * 32 + ct * 16 + kg * 4 + rg;
                int px = bx * 64 + pw * 32 + pt * 16 + r15;
                int poh = px / OW, pow_ = px % OW;
                float v = acc[ct][pt][rg] + bias[co];
                outp[((size_t)(bz * CO + co) * OSH + (poh + OR0)) * OSW + (pow_ + OC0)] = lrelu(v);
            }
}

// ---------------------------------------------------------------------------
// FC as bf16 hi/lo split-GEMM on MFMA. C[m][n] = sum_k S[m][k]*W[n][k].
// M=1024, N=256, K=12800, ksplit=16 (slice 800 = 25 x BK32).
// Tile 128m x 64n, 4 waves; wave wv owns m-rows [wv*32, wv*32+32) x all 64 n
// -> 2x4 16x16 frags, 24 MFMA/K-step. Same LDS discipline as conv_mfma_k.
// A-frag = S rows (C row = m), B-frag = W rows (C col = n).
// ---------------------------------------------------------------------------
__global__ __launch_bounds__(256, 2) void fc_mfma_k(
    const unsigned* __restrict__ Sp,   // packed [1024][12800]
    const unsigned* __restrict__ Wp,   // packed [256][12800]
    float* __restrict__ part)          // [16][1024][256]
{
    // dword offsets per buffer: AH 2560 | AL 2560 | BH 1280 | BL 1280 = 7680
    __shared__ unsigned ldsu[15360];
    short* const lds = (short*)ldsu;

    const int tid  = threadIdx.x;
    const int lane = tid & 63;
    const int wv   = tid >> 6;
    const int bn = blockIdx.x, bm = blockIdx.y, ks = blockIdx.z;

    // staging roles: A row=tid&127, chunks {ca, ca+2}; B row=tid&63, chunk cb
    const int ra = tid & 127, ca = tid >> 7;
    const int rb = tid & 63,  cb = tid >> 6;
    const unsigned* __restrict__ aptr = Sp + (size_t)(bm * 128 + ra) * 12800 + ks * 800;
    const unsigned* __restrict__ bptr = Wp + (size_t)(bn * 64 + rb) * 12800 + ks * 800;

    unsigned Au[16], Bu[8];
    auto gather = [&](int it) {
        const int k0 = it * 32;
#pragma unroll
        for (int j = 0; j < 8; ++j) {
            Au[j]     = aptr[k0 + ca * 8 + j];
            Au[8 + j] = aptr[k0 + (ca + 2) * 8 + j];
            Bu[j]     = bptr[k0 + cb * 8 + j];
        }
    };

    f32x4 acc[2][4] = {};
    const int r15 = lane & 15, kg = lane >> 4;

    gather(0);
    for (int it = 0; it < 25; ++it) {
        const int p = it & 1;
        {
            const int base = p * 7680;
            uint4 vh, vl;
            // A chunk ca
            vh.x = pack_lo16(Au[1], Au[0]); vl.x = pack_hi16(Au[1], Au[0]);
            vh.y = pack_lo16(Au[3], Au[2]); vl.y = pack_hi16(Au[3], Au[2]);
            vh.z = pack_lo16(Au[5], Au[4]); vl.z = pack_hi16(Au[5], Au[4]);
            vh.w = pack_lo16(Au[7], Au[6]); vl.w = pack_hi16(Au[7], Au[6]);
            *(uint4*)&ldsu[base + ra * 20 + ca * 4]        = vh;
            *(uint4*)&ldsu[base + 2560 + ra * 20 + ca * 4] = vl;
            // A chunk ca+2
            vh.x = pack_lo16(Au[9],  Au[8]);  vl.x = pack_hi16(Au[9],  Au[8]);
            vh.y = pack_lo16(Au[11], Au[10]); vl.y = pack_hi16(Au[11], Au[10]);
            vh.z = pack_lo16(Au[13], Au[12]); vl.z = pack_hi16(Au[13], Au[12]);
            vh.w = pack_lo16(Au[15], Au[14]); vl.w = pack_hi16(Au[15], Au[14]);
            *(uint4*)&ldsu[base + ra * 20 + (ca + 2) * 4]        = vh;
            *(uint4*)&ldsu[base + 2560 + ra * 20 + (ca + 2) * 4] = vl;
            // B chunk cb
            vh.x = pack_lo16(Bu[1], Bu[0]); vl.x = pack_hi16(Bu[1], Bu[0]);
            vh.y = pack_lo16(Bu[3], Bu[2]); vl.y = pack_hi16(Bu[3], Bu[2]);
            vh.z = pack_lo16(Bu[5], Bu[4]); vl.z = pack_hi16(Bu[5], Bu[4]);
            vh.w = pack_lo16(Bu[7], Bu[6]); vl.w = pack_hi16(Bu[7], Bu[6]);
            *(uint4*)&ldsu[base + 5120 + rb * 20 + cb * 4] = vh;
            *(uint4*)&ldsu[base + 6400 + rb * 20 + cb * 4] = vl;
        }
        __syncthreads();
        if (it + 1 < 25) gather(it + 1);

        const short* AsH = lds + (p * 7680) * 2;
        const short* AsL = AsH + 5120;
        const short* BsH = AsH + 10240;
        const short* BsL = AsH + 12800;
        short8 aH[2], aL[2], bH[4], bL[4];
#pragma unroll
        for (int mq = 0; mq < 2; ++mq) {
            const int rr = (wv * 32 + mq * 16 + r15) * 40 + kg * 8;
            aH[mq] = *(const short8*)&AsH[rr];
            aL[mq] = *(const short8*)&AsL[rr];
        }
#pragma unroll
        for (int nq = 0; nq < 4; ++nq) {
            const int rr = (nq * 16 + r15) * 40 + kg * 8;
            bH[nq] = *(const short8*)&BsH[rr];
            bL[nq] = *(const short8*)&BsL[rr];
        }
#pragma unroll
        for (int mq = 0; mq < 2; ++mq)
#pragma unroll
            for (int nq = 0; nq < 4; ++nq) {
                acc[mq][nq] = __builtin_amdgcn_mfma_f32_16x16x32_bf16(aH[mq], bH[nq], acc[mq][nq], 0, 0, 0);
                acc[mq][nq] = __builtin_amdgcn_mfma_f32_16x16x32_bf16(aH[mq], bL[nq], acc[mq][nq], 0, 0, 0);
                acc[mq][nq] = __builtin_amdgcn_mfma_f32_16x16x32_bf16(aL[mq], bH[nq], acc[mq][nq], 0, 0, 0);
            }
        __syncthreads();
    }

    // C/D: col = lane&15 -> n, row = (lane>>4)*4+reg -> m
    float* __restrict__ po = part + (size_t)ks * 262144;
#pragma unroll
    for (int mq = 0; mq < 2; ++mq)
#pragma unroll
        for (int nq = 0; nq < 4; ++nq)
#pragma unroll
            for (int rg = 0; rg < 4; ++rg) {
                int m = bm * 128 + wv * 32 + mq * 16 + kg * 4 + rg;
                int ncol = bn * 64 + nq * 16 + r15;
                po[(size_t)m * 256 + ncol] = acc[mq][nq][rg];
            }
}

// ---------------------------------------------------------------------------
// x -> x_pad [32*3][228][228], 2-pixel zero border.
// ---------------------------------------------------------------------------
__global__ __launch_bounds__(256) void pad_x_k(const float* __restrict__ x,
                                               float* __restrict__ xp) {
    int blk = blockIdx.x;              // 32*3*57
    int r4 = blk % 57, ic = blk / 57;
    int wid = threadIdx.x >> 6, lane = threadIdx.x & 63;
    int row = r4 * 4 + wid;
    const float* __restrict__ src = x + (size_t)ic * 224 * 224 + (size_t)(row - 2) * 224;
    float* __restrict__ dst = xp + (size_t)ic * 228 * 228 + (size_t)row * 228;
    bool rok = (row >= 2) && (row < 226);
    for (int c = lane; c < 228; c += 64) {
        float v = 0.0f;
        if (rok && c >= 2 && c < 226) v = src[c - 2];
        dst[c] = v;
    }
}

// c1p plane = 116 x 120; data ow at layout col ow+4 (border cols 2,3,116,117).
__global__ __launch_bounds__(256) void zb_c1p_k(float* __restrict__ p) {
    float* base = p + (size_t)blockIdx.x * (116 * 120);
    for (int t = threadIdx.x; t < 928; t += 256) {
        int idx;
        if (t < 480) {
            int r = t / 120, c = t - r * 120;
            int row = (r < 2) ? r : r + 112;
            idx = row * 120 + c;
        } else {
            int s = t - 480;
            int r = s >> 2, c = s & 3;
            int col = (c < 2) ? (c + 2) : (c + 114);
            idx = (r + 2) * 120 + col;
        }
        base[idx] = 0.0f;
    }
}

// c2p plane = 58 x 64; data ow at layout col ow+4 (border cols 3,60).
__global__ __launch_bounds__(64) void zb_c2p_k(float* __restrict__ p) {
    float* base = p + (size_t)blockIdx.x * (58 * 64);
    for (int t = threadIdx.x; t < 240; t += 64) {
        int idx;
        if (t < 128) {
            int r = t >> 6, c = t & 63;
            idx = (r ? 57 : 0) * 64 + c;
        } else {
            int s = t - 128;
            int r = (s >> 1) + 1;
            idx = r * 64 + ((s & 1) ? 60 : 3);
        }
        base[idx] = 0.0f;
    }
}

// ---------------------------------------------------------------------------
// ROI bilinear sampling — now writes PACKED hi/lo dwords (FC consumes packed).
// Layout/content unchanged otherwise (reference reshape quirk preserved).
// ---------------------------------------------------------------------------
__global__ __launch_bounds__(256) void roi_k(const float* __restrict__ feat,
                                             const float* __restrict__ roi,
                                             unsigned* __restrict__ S) {
    int b = blockIdx.x >> 5;
    int r = blockIdx.x & 31;
    const float* rr = roi + (size_t)(b * 32 + r) * 7;

    __shared__ int   offA[100], offB[100], offC[100], offD[100];
    __shared__ float wA[100], wB[100], wC[100], wD[100];

    int tid = threadIdx.x;
    if (tid < 100) {
        int i = tid / 10, j = tid % 10;
        float cx = rr[0], cy = rr[1];
        float W1 = rr[2], W2 = rr[3], H1 = rr[4], H2 = rr[5], psi = rr[6];
        float offx = ((float)j - 4.5f) / 10.0f;
        float offy = ((float)i - 4.5f) / 10.0f;
        float gx = offx * (W1 + W2) - (W1 - W2) * 0.5f;
        float gy = offy * (H1 + H2) - (H1 - H2) * 0.5f;
        float sn = sinf(psi), cs = cosf(psi);
        float xs = gx * cs + gy * sn + cx;
        float ys = -gx * sn + gy * cs + cy;

        float x0f = floorf(xs), y0f = floorf(ys);
        int x0 = (int)x0f, x1 = x0 + 1;
        int y0 = (int)y0f, y1 = y0 + 1;
        x0 = min(max(x0, 0), 55); x1 = min(max(x1, 0), 55);
        y0 = min(max(y0, 0), 55); y1 = min(max(y1, 0), 55);
        float fx0 = (float)x0, fx1 = (float)x1;
        float fy0 = (float)y0, fy1 = (float)y1;
        float step = (fx1 - fx0) * (fy1 - fy0);
        step = fminf(fmaxf(step, 0.001f), 2.0f);
        float inv = 1.0f / step;
        wA[tid] = (fx1 - xs) * (fy1 - ys) * inv;
        wB[tid] = (fx1 - xs) * (ys - fy0) * inv;
        wC[tid] = (xs - fx0) * (fy1 - ys) * inv;
        wD[tid] = (xs - fx0) * (ys - fy0) * inv;
        offA[tid] = y0 * 56 + x0;
        offB[tid] = y1 * 56 + x0;
        offC[tid] = y0 * 56 + x1;
        offD[tid] = y1 * 56 + x1;
    }
    __syncthreads();

    const float* __restrict__ fb = feat + (size_t)b * 128 * 3136;
    unsigned* __restrict__ outb = S + ((size_t)b * 128 * 32 + r) * 100;
    int c = tid / 100;
    int p = tid - c * 100;
    for (int t = tid; t < 12800; t += 256) {
        const float* f = fb + c * 3136;
        float v = wA[p] * f[offA[p]] + wB[p] * f[offB[p]] +
                  wC[p] * f[offC[p]] + wD[p] * f[offD[p]];
        outb[(size_t)c * 3200 + p] = pack_bf16pair(v);
        p += 56; c += 2;
        if (p >= 100) { p -= 100; ++c; }
    }
}

__global__ __launch_bounds__(256) void fc2_reduce_k(const float* __restrict__ part,
                                                    const float* __restrict__ bias,
                                                    float* __restrict__ out) {
    int i = blockIdx.x * 256 + threadIdx.x;   // 0..262143
    float s = bias[i & 255];
    for (int ks = 0; ks < 16; ++ks) s += part[(size_t)ks * 262144 + i];
    out[i] = s;
}

// ---------------------------------------------------------------------------
extern "C" void kernel_launch(void* const* d_in, const int* in_sizes, int n_in,
                              void* d_out, int out_size, void* d_ws, size_t ws_size,
                              hipStream_t stream) {
    const float* x   = (const float*)d_in[0];
    const float* ROI = (const float*)d_in[1];
    const float* w1  = (const float*)d_in[2];
    const float* b1  = (const float*)d_in[3];
    const float* w2  = (const float*)d_in[4];
    const float* b2  = (const float*)d_in[5];
    const float* w3  = (const float*)d_in[6];
    const float* b3  = (const float*)d_in[7];
    const float* fcw = (const float*)d_in[8];
    const float* fcb = (const float*)d_in[9];
    float* out = (float*)d_out;

    char* ws = (char*)d_ws;
    // Workspace:
    //  c1p  [0,           57,016,320)  conv1 -> (in-place pack) -> conv2
    //  c2p  [57,016,320,  87,425,024)  conv2 -> (in-place pack) -> conv3
    //  xpad [87,425,024, 107,386,880)  pad  -> conv1        (dead after conv1)
    //  wT1  [107,386,880, 107,397,120) fp32 (conv1)
    //  wT2p [107,397,120, 107,601,920) packed (conv2)
    //  wT3p [107,601,920, 107,896,832) packed (conv3)
    //  c3   [0,           51,380,224)  conv3 -> roi      (c1p dead)
    //  S    [57,016,320, 109,445,120)  roi (PACKED) -> fc  (c2p dead)
    //  wfcp [0,           13,107,200)  packed fcw          (c3 dead after roi)
    //  part [16,777,216,  33,554,432)  fc -> reduce        (inside dead c3)
    float* c1p  = (float*)(ws);
    float* c2p  = (float*)(ws + 57016320);
    float* xpad = (float*)(ws + 87425024);
    float* wT1  = (float*)(ws + 107386880);
    unsigned* wT2p = (unsigned*)(ws + 107397120);
    unsigned* wT3p = (unsigned*)(ws + 107601920);
    float* c3   = (float*)(ws);
    unsigned* S = (unsigned*)(ws + 57016320);
    unsigned* wfcp = (unsigned*)(ws);
    float* part = (float*)(ws + 16777216);

    wtr_k<32, 75, 80><<<10, 256, 0, stream>>>(w1, wT1);
    wtr_pack_k<64, 800, 800><<<200, 256, 0, stream>>>(w2, wT2p);
    wtr_pack_k<128, 576, 576><<<288, 256, 0, stream>>>(w3, wT3p);
    pad_x_k<<<32 * 3 * 57, 256, 0, stream>>>(x, xpad);
    zb_c1p_k<<<1024, 256, 0, stream>>>(c1p);
    zb_c2p_k<<<2048, 64, 0, stream>>>(c2p);

    // conv1 (fp32): 32co x 128px, 4x4 micro, 256 thr, BK=16, MINW=4
    conv_gemm_k<3, 2, 5, 5, 75, 80, 228, 228, 0, 112, 12544,
                32, 128, 4, 4, 116, 120, 2, 4, 4, 256, 16>
        <<<3136, 256, 0, stream>>>(xpad, wT1, b1, c1p);

    // conv2 (MFMA): in-place pack c1p, then 64co x 100352px, K=800
    split_pack_k<<<4096, 256, 0, stream>>>(c1p, (unsigned*)c1p, 14254080);
    conv_mfma_k<32, 2, 5, 5, 800, 116, 120, 2, 64, 56, 58, 64, 1, 4>
        <<<dim3(49, 1, 32), 256, 0, stream>>>((unsigned*)c1p, wT2p, b2, c2p);

    // conv3 (MFMA): in-place pack c2p, then 128co x 100352px, K=576
    split_pack_k<<<4096, 256, 0, stream>>>(c2p, (unsigned*)c2p, 7602176);
    conv_mfma_k<64, 1, 3, 3, 576, 58, 64, 3, 128, 56, 56, 56, 0, 0>
        <<<dim3(49, 2, 32), 256, 0, stream>>>((unsigned*)c2p, wT3p, b3, c3);

    // ROI sampling -> packed S
    roi_k<<<1024, 256, 0, stream>>>(c3, ROI, S);
    // FC (MFMA): pack fcw, split-K 16 + reduce
    split_pack_k<<<4096, 256, 0, stream>>>(fcw, wfcp, 3276800);
    fc_mfma_k<<<dim3(4, 8, 16), 256, 0, stream>>>(S, wfcp, part);
    fc2_reduce_k<<<1024, 256, 0, stream>>>(part, fcb, out);
}

// Round 10
// 426.651 us; speedup vs baseline: 1.5058x; 1.0716x over previous
//
#include <hip/hip_runtime.h>
#include <hip/hip_bf16.h>

#define LEAK 0.2f

__device__ __forceinline__ float lrelu(float a) { return a > 0.0f ? a : LEAK * a; }

typedef __attribute__((ext_vector_type(8))) short short8;
typedef __attribute__((ext_vector_type(4))) float f32x4;

// bf16 RNE rounding done manually (no dependence on __hip_bfloat16 ABI).
__device__ __forceinline__ unsigned short bf16_hi_bits(float x) {
    unsigned u = __builtin_bit_cast(unsigned, x);
    unsigned r = u + 0x7fffu + ((u >> 16) & 1u);
    return (unsigned short)(r >> 16);
}
__device__ __forceinline__ float bf16_to_f32(unsigned short h) {
    unsigned u = ((unsigned)h) << 16;
    return __builtin_bit_cast(float, u);
}
__device__ __forceinline__ unsigned pack_bf16pair(float x) {
    unsigned short h = bf16_hi_bits(x);
    float lo = x - bf16_to_f32(h);
    return (unsigned)h | ((unsigned)bf16_hi_bits(lo) << 16);
}

// v_perm_b32 pair-packers: dwords are packed {hi-bf16 in low16, lo-bf16 in high16}.
__device__ __forceinline__ unsigned pack_lo16(unsigned o, unsigned e) {
    return __builtin_amdgcn_perm(o, e, 0x05040100u);
}
__device__ __forceinline__ unsigned pack_hi16(unsigned o, unsigned e) {
    return __builtin_amdgcn_perm(o, e, 0x07060302u);
}

// ---------------------------------------------------------------------------
// Implicit-GEMM conv + leaky ReLU (fp32 vector path — conv1 only now).
// ---------------------------------------------------------------------------
template<int CI, int ST, int KH, int KW, int KIN, int KP,
         int PIH, int PIW, int LP, int OW, int PPI,
         int CO, int NT, int MR, int NR, int OSH, int OSW, int OR0, int OC0,
         int MINW, int NTHR, int BK>
__global__ __launch_bounds__(NTHR, MINW) void conv_gemm_k(
    const float* __restrict__ in,    // padded input [img*CI + ci][PIH][PIW]
    const float* __restrict__ wT,    // [KP][CO]
    const float* __restrict__ bias,
    float* __restrict__ out)
{
    constexpr int KT  = KP / BK;
    constexpr int TXW = NT / 4;         // B staging pixel-quads per k-row
    constexpr int TXN = NT / NR;        // compute columns
    constexpr int BT  = BK * NT / 4;
    constexpr int AT  = BK * CO / 4;
    constexpr int BI  = (BT + NTHR - 1) / NTHR;
    constexpr int AI  = (AT + NTHR - 1) / NTHR;
    constexpr int ASZ = BK * CO;
    constexpr int BSZ = BK * NT;

    __shared__ float sm[2 * ASZ + 2 * BSZ];

    const int tid = threadIdx.x;
    const int bx  = blockIdx.x;
    const int tx  = tid % TXN;
    const int ty  = tid / TXN;

    // ---- per-thread staging geometry (K-independent) ----
    int bofs[BI], bkl[BI], bcol[BI];
#pragma unroll
    for (int q = 0; q < BI; ++q) {
        int task = tid + q * NTHR;
        if ((BT % NTHR == 0) || task < BT) {
            int kl  = task / TXW;
            int pxq = task % TXW;
            int px0 = bx * NT + pxq * 4;
            int img = px0 / PPI;
            int n   = px0 % PPI;
            int oh  = n / OW, ow = n % OW;
            bofs[q] = ((img * CI) * PIH + oh * ST) * PIW + ow * ST + LP;
            bkl[q]  = kl;
            bcol[q] = (NR == 8) ? (((pxq & 1) * (TXW / 2) + (pxq >> 1)) * 4)
                                : (pxq * 4);
        }
    }

    float  br[BI][4];
    float4 ar[AI];

    auto gather = [&](int it) {
        int k0 = it * BK;
#pragma unroll
        for (int q = 0; q < BI; ++q) {
            int task = tid + q * NTHR;
            if ((BT % NTHR == 0) || task < BT) {
                int k = k0 + bkl[q];
                if (KP > KIN) k = min(k, KIN - 1);   // padded-K tail (weights 0)
                int ci  = k / (KH * KW);
                int rem = k - ci * (KH * KW);
                int kh  = rem / KW;
                int kw  = rem - kh * KW;
                const float* __restrict__ s = in + bofs[q] + (ci * PIH + kh) * PIW + kw;
                br[q][0] = s[0]; br[q][1] = s[ST]; br[q][2] = s[2 * ST]; br[q][3] = s[3 * ST];
            }
        }
#pragma unroll
        for (int p = 0; p < AI; ++p) {
            int task = tid + p * NTHR;
            if ((AT % NTHR == 0) || task < AT)
                ar[p] = *(const float4*)&wT[(size_t)k0 * CO + task * 4];
        }
    };

    float acc[MR][NR];
#pragma unroll
    for (int j = 0; j < MR; ++j) {
        float bv = bias[ty * MR + j];
#pragma unroll
        for (int i = 0; i < NR; ++i) acc[j][i] = bv;
    }

    gather(0);
    for (int it = 0; it < KT; ++it) {
        const int p = it & 1;
        float* __restrict__ Asb = sm + p * ASZ;
        float* __restrict__ Bsb = sm + 2 * ASZ + p * BSZ;
#pragma unroll
        for (int pa = 0; pa < AI; ++pa) {
            int task = tid + pa * NTHR;
            if ((AT % NTHR == 0) || task < AT)
                *(float4*)&Asb[task * 4] = ar[pa];
        }
#pragma unroll
        for (int q = 0; q < BI; ++q) {
            int task = tid + q * NTHR;
            if ((BT % NTHR == 0) || task < BT)
                *(float4*)&Bsb[bkl[q] * NT + bcol[q]] =
                    make_float4(br[q][0], br[q][1], br[q][2], br[q][3]);
        }
        __syncthreads();
        if (it + 1 < KT) gather(it + 1);
#pragma unroll
        for (int k = 0; k < BK; ++k) {
            float b[NR], a[MR];
            if (NR == 8) {
                *(float4*)&b[0] = *(const float4*)&Bsb[k * NT + tx * 4];
                *(float4*)&b[4] = *(const float4*)&Bsb[k * NT + NT / 2 + tx * 4];
            } else {
#pragma unroll
                for (int i = 0; i < NR / 4; ++i)
                    *(float4*)&b[4 * i] = *(const float4*)&Bsb[k * NT + tx * NR + 4 * i];
            }
#pragma unroll
            for (int j = 0; j < MR / 4; ++j)
                *(float4*)&a[4 * j] = *(const float4*)&Asb[k * CO + ty * MR + 4 * j];
#pragma unroll
            for (int j = 0; j < MR; ++j)
#pragma unroll
                for (int i = 0; i < NR; ++i)
                    acc[j][i] += a[j] * b[i];
        }
    }

    {
        int pxs = bx * NT + tx * NR;
        int img = pxs / PPI;
        int n   = pxs % PPI;
        int oh  = n / OW, ow = n % OW;
#pragma unroll
        for (int j = 0; j < MR; ++j) {
            int co = ty * MR + j;
            size_t off = (((size_t)img * CO + co) * OSH + (oh + OR0)) * OSW + (ow + OC0);
#pragma unroll
            for (int q = 0; q < NR / 4; ++q) {
                float4 v = make_float4(lrelu(acc[j][4 * q + 0]), lrelu(acc[j][4 * q + 1]),
                                       lrelu(acc[j][4 * q + 2]), lrelu(acc[j][4 * q + 3]));
                *(float4*)&out[off + 4 * q] = v;
            }
        }
    }
}

// ---------------------------------------------------------------------------
// Weight transpose fp32 (conv1): wT[k][co] = w[co][k], K padded with zeros.
// ---------------------------------------------------------------------------
template<int CO, int KIN, int KP>
__global__ __launch_bounds__(256) void wtr_k(const float* __restrict__ w,
                                             float* __restrict__ wT) {
    int i = blockIdx.x * 256 + threadIdx.x;
    if (i >= KP * CO) return;
    int k = i / CO, co = i % CO;
    wT[i] = (k < KIN) ? w[(size_t)co * KIN + k] : 0.0f;
}

// Weight transpose + bf16 hi/lo pack (conv2/conv3 MFMA path).
template<int CO, int KIN, int KP>
__global__ __launch_bounds__(256) void wtr_pack_k(const float* __restrict__ w,
                                                  unsigned* __restrict__ wTp) {
    int i = blockIdx.x * 256 + threadIdx.x;
    if (i >= KP * CO) return;
    int k = i / CO, co = i % CO;
    float x = (k < KIN) ? w[(size_t)co * KIN + k] : 0.0f;
    wTp[i] = pack_bf16pair(x);
}

// ---------------------------------------------------------------------------
// Pack fp32 -> dword {bf16 hi, bf16 lo}. In-place safe (same-index RMW).
// ---------------------------------------------------------------------------
__global__ __launch_bounds__(256) void split_pack_k(const float* __restrict__ src,
                                                    unsigned* __restrict__ dst, int n) {
    for (int i = blockIdx.x * 256 + threadIdx.x; i < n; i += gridDim.x * 256) {
        dst[i] = pack_bf16pair(src[i]);
    }
}

// ---------------------------------------------------------------------------
// Conv as bf16 hi/lo split-GEMM on MFMA (conv2 and conv3) — v3.
// v2 measured: VALU 30% / MFMA 20% / LDS ~38% / HBM 16% / Occ 27% (2 blocks/CU,
// capped by 43.5KB dbuf LDS) => latency/barrier-bound. v3: SINGLE-buffer LDS
// (20.5KB + offtab -> ~6 blocks/CU) with 2 barriers/iter; register prefetch
// (gather(it+1) between barriers) keeps global latency hidden; cross-block
// overlap hides the barriers. Data layout identical to verified v2.
// ---------------------------------------------------------------------------
template<int CI, int ST, int KH, int KW, int KP,
         int PIH, int PIW, int LP,
         int CO, int OW, int OSH, int OSW, int OR0, int OC0>
__global__ __launch_bounds__(256, 4) void conv_mfma_k(
    const unsigned* __restrict__ src,   // packed act [img*CI+ci][PIH][PIW]
    const unsigned* __restrict__ wp,    // packed wT  [KP][CO]
    const float* __restrict__ bias,
    float* __restrict__ outp)
{
    constexpr int KT = KP / 32;
    __shared__ unsigned ldsu[5120];     // 4 arrays x 64 rows x 20 dw (single buf)
    __shared__ int offtab[KP];
    short* const lds = (short*)ldsu;

    const int tid  = threadIdx.x;
    const int lane = tid & 63;
    const int wv   = tid >> 6;          // wave 0..3
    const int bx   = blockIdx.x;        // 49 px tiles
    const int by   = blockIdx.y;        // CO/64 co tiles
    const int bz   = blockIdx.z;        // 32 imgs

    for (int k = tid; k < KP; k += 256) {
        int ci = k / (KH * KW), r = k - ci * (KH * KW);
        int kh = r / KW, kw = r - kh * KW;
        offtab[k] = (ci * PIH + kh) * PIW + kw;
    }
    __syncthreads();

    const int row = lane;               // staging row; k-slot = wave (8 k each)
    const int n   = bx * 64 + row;      // 0..3135
    const int oh  = n / OW, ow = n % OW;
    const unsigned* __restrict__ bsrc =
        src + ((size_t)(bz * CI) * PIH + oh * ST) * PIW + ow * ST + LP;
    const unsigned* __restrict__ wsrc = wp + (size_t)(wv * 8) * CO + by * 64 + row;

    unsigned Au[8], Bu[8];
    auto gather = [&](int it) {
        const int k0 = it * 32 + wv * 8;
        int4 o0 = *(const int4*)&offtab[k0];       // broadcast ds_read
        int4 o1 = *(const int4*)&offtab[k0 + 4];
        const unsigned* __restrict__ wk = wsrc + (size_t)it * 32 * CO;
#pragma unroll
        for (int j = 0; j < 8; ++j) Au[j] = wk[j * CO];
        Bu[0] = bsrc[o0.x]; Bu[1] = bsrc[o0.y]; Bu[2] = bsrc[o0.z]; Bu[3] = bsrc[o0.w];
        Bu[4] = bsrc[o1.x]; Bu[5] = bsrc[o1.y]; Bu[6] = bsrc[o1.z]; Bu[7] = bsrc[o1.w];
    };

    f32x4 acc[2][2] = {};

    const int cw = wv & 1, pw = wv >> 1;
    const int r15 = lane & 15, kg = lane >> 4;

    gather(0);
    for (int it = 0; it < KT; ++it) {
        {
            const int widx = row * 20 + wv * 4;    // dword index within array
            uint4 vh, vl;
            vh.x = pack_lo16(Au[1], Au[0]); vl.x = pack_hi16(Au[1], Au[0]);
            vh.y = pack_lo16(Au[3], Au[2]); vl.y = pack_hi16(Au[3], Au[2]);
            vh.z = pack_lo16(Au[5], Au[4]); vl.z = pack_hi16(Au[5], Au[4]);
            vh.w = pack_lo16(Au[7], Au[6]); vl.w = pack_hi16(Au[7], Au[6]);
            *(uint4*)&ldsu[0 * 1280 + widx] = vh;
            *(uint4*)&ldsu[1 * 1280 + widx] = vl;
            vh.x = pack_lo16(Bu[1], Bu[0]); vl.x = pack_hi16(Bu[1], Bu[0]);
            vh.y = pack_lo16(Bu[3], Bu[2]); vl.y = pack_hi16(Bu[3], Bu[2]);
            vh.z = pack_lo16(Bu[5], Bu[4]); vl.z = pack_hi16(Bu[5], Bu[4]);
            vh.w = pack_lo16(Bu[7], Bu[6]); vl.w = pack_hi16(Bu[7], Bu[6]);
            *(uint4*)&ldsu[2 * 1280 + widx] = vh;
            *(uint4*)&ldsu[3 * 1280 + widx] = vl;
        }
        __syncthreads();
        if (it + 1 < KT) gather(it + 1);

        const short* AsH = lds + 0 * 2560;
        const short* AsL = lds + 1 * 2560;
        const short* BsH = lds + 2 * 2560;
        const short* BsL = lds + 3 * 2560;
        short8 aH[2], aL[2], bH[2], bL[2];
#pragma unroll
        for (int tq = 0; tq < 2; ++tq) {
            const int ra = (cw * 32 + tq * 16 + r15) * 40 + kg * 8;
            aH[tq] = *(const short8*)&AsH[ra];
            aL[tq] = *(const short8*)&AsL[ra];
            const int rb = (pw * 32 + tq * 16 + r15) * 40 + kg * 8;
            bH[tq] = *(const short8*)&BsH[rb];
            bL[tq] = *(const short8*)&BsL[rb];
        }
#pragma unroll
        for (int ct = 0; ct < 2; ++ct)
#pragma unroll
            for (int pt = 0; pt < 2; ++pt) {
                acc[ct][pt] = __builtin_amdgcn_mfma_f32_16x16x32_bf16(aH[ct], bH[pt], acc[ct][pt], 0, 0, 0);
                acc[ct][pt] = __builtin_amdgcn_mfma_f32_16x16x32_bf16(aH[ct], bL[pt], acc[ct][pt], 0, 0, 0);
                acc[ct][pt] = __builtin_amdgcn_mfma_f32_16x16x32_bf16(aL[ct], bH[pt], acc[ct][pt], 0, 0, 0);
            }
        __syncthreads();
    }

    // C/D: col = lane&15 -> px, row = (lane>>4)*4+reg -> co
#pragma unroll
    for (int ct = 0; ct < 2; ++ct)
#pragma unroll
        for (int pt = 0; pt < 2; ++pt)
#pragma unroll
            for (int rg = 0; rg < 4; ++rg) {
                int co = by * 64 + cw * 32 + ct * 16 + kg * 4 + rg;
                int px = bx * 64 + pw * 32 + pt * 16 + r15;
                int poh = px / OW, pow_ = px % OW;
                float v = acc[ct][pt][rg] + bias[co];
                outp[((size_t)(bz * CO + co) * OSH + (poh + OR0)) * OSW + (pow_ + OC0)] = lrelu(v);
            }
}

// ---------------------------------------------------------------------------
// FC as bf16 hi/lo split-GEMM on MFMA — v2 (single-buffer LDS, 30.7KB -> ~5
// blocks/CU). C[m][n] = sum_k S[m][k]*W[n][k]. M=1024, N=256, K=12800,
// ksplit=16 (slice 800 = 25 x BK32). Tile 128m x 64n, 4 waves.
// ---------------------------------------------------------------------------
__global__ __launch_bounds__(256, 4) void fc_mfma_k(
    const unsigned* __restrict__ Sp,   // packed [1024][12800]
    const unsigned* __restrict__ Wp,   // packed [256][12800]
    float* __restrict__ part)          // [16][1024][256]
{
    // dword offsets: AH 0 | AL 2560 | BH 5120 | BL 6400 ; total 7680 dw
    __shared__ unsigned ldsu[7680];
    short* const lds = (short*)ldsu;

    const int tid  = threadIdx.x;
    const int lane = tid & 63;
    const int wv   = tid >> 6;
    const int bn = blockIdx.x, bm = blockIdx.y, ks = blockIdx.z;

    // staging roles: A row=tid&127, chunks {ca, ca+2}; B row=tid&63, chunk cb
    const int ra = tid & 127, ca = tid >> 7;
    const int rb = tid & 63,  cb = tid >> 6;
    const unsigned* __restrict__ aptr = Sp + (size_t)(bm * 128 + ra) * 12800 + ks * 800;
    const unsigned* __restrict__ bptr = Wp + (size_t)(bn * 64 + rb) * 12800 + ks * 800;

    unsigned Au[16], Bu[8];
    auto gather = [&](int it) {
        const int k0 = it * 32;
#pragma unroll
        for (int j = 0; j < 8; ++j) {
            Au[j]     = aptr[k0 + ca * 8 + j];
            Au[8 + j] = aptr[k0 + (ca + 2) * 8 + j];
            Bu[j]     = bptr[k0 + cb * 8 + j];
        }
    };

    f32x4 acc[2][4] = {};
    const int r15 = lane & 15, kg = lane >> 4;

    gather(0);
    for (int it = 0; it < 25; ++it) {
        {
            uint4 vh, vl;
            // A chunk ca
            vh.x = pack_lo16(Au[1], Au[0]); vl.x = pack_hi16(Au[1], Au[0]);
            vh.y = pack_lo16(Au[3], Au[2]); vl.y = pack_hi16(Au[3], Au[2]);
            vh.z = pack_lo16(Au[5], Au[4]); vl.z = pack_hi16(Au[5], Au[4]);
            vh.w = pack_lo16(Au[7], Au[6]); vl.w = pack_hi16(Au[7], Au[6]);
            *(uint4*)&ldsu[ra * 20 + ca * 4]        = vh;
            *(uint4*)&ldsu[2560 + ra * 20 + ca * 4] = vl;
            // A chunk ca+2
            vh.x = pack_lo16(Au[9],  Au[8]);  vl.x = pack_hi16(Au[9],  Au[8]);
            vh.y = pack_lo16(Au[11], Au[10]); vl.y = pack_hi16(Au[11], Au[10]);
            vh.z = pack_lo16(Au[13], Au[12]); vl.z = pack_hi16(Au[13], Au[12]);
            vh.w = pack_lo16(Au[15], Au[14]); vl.w = pack_hi16(Au[15], Au[14]);
            *(uint4*)&ldsu[ra * 20 + (ca + 2) * 4]        = vh;
            *(uint4*)&ldsu[2560 + ra * 20 + (ca + 2) * 4] = vl;
            // B chunk cb
            vh.x = pack_lo16(Bu[1], Bu[0]); vl.x = pack_hi16(Bu[1], Bu[0]);
            vh.y = pack_lo16(Bu[3], Bu[2]); vl.y = pack_hi16(Bu[3], Bu[2]);
            vh.z = pack_lo16(Bu[5], Bu[4]); vl.z = pack_hi16(Bu[5], Bu[4]);
            vh.w = pack_lo16(Bu[7], Bu[6]); vl.w = pack_hi16(Bu[7], Bu[6]);
            *(uint4*)&ldsu[5120 + rb * 20 + cb * 4] = vh;
            *(uint4*)&ldsu[6400 + rb * 20 + cb * 4] = vl;
        }
        __syncthreads();
        if (it + 1 < 25) gather(it + 1);

        const short* AsH = lds;
        const short* AsL = AsH + 5120;
        const short* BsH = AsH + 10240;
        const short* BsL = AsH + 12800;
        short8 aH[2], aL[2], bH[4], bL[4];
#pragma unroll
        for (int mq = 0; mq < 2; ++mq) {
            const int rr = (wv * 32 + mq * 16 + r15) * 40 + kg * 8;
            aH[mq] = *(const short8*)&AsH[rr];
            aL[mq] = *(const short8*)&AsL[rr];
        }
#pragma unroll
        for (int nq = 0; nq < 4; ++nq) {
            const int rr = (nq * 16 + r15) * 40 + kg * 8;
            bH[nq] = *(const short8*)&BsH[rr];
            bL[nq] = *(const short8*)&BsL[rr];
        }
#pragma unroll
        for (int mq = 0; mq < 2; ++mq)
#pragma unroll
            for (int nq = 0; nq < 4; ++nq) {
                acc[mq][nq] = __builtin_amdgcn_mfma_f32_16x16x32_bf16(aH[mq], bH[nq], acc[mq][nq], 0, 0, 0);
                acc[mq][nq] = __builtin_amdgcn_mfma_f32_16x16x32_bf16(aH[mq], bL[nq], acc[mq][nq], 0, 0, 0);
                acc[mq][nq] = __builtin_amdgcn_mfma_f32_16x16x32_bf16(aL[mq], bH[nq], acc[mq][nq], 0, 0, 0);
            }
        __syncthreads();
    }

    // C/D: col = lane&15 -> n, row = (lane>>4)*4+reg -> m
    float* __restrict__ po = part + (size_t)ks * 262144;
#pragma unroll
    for (int mq = 0; mq < 2; ++mq)
#pragma unroll
        for (int nq = 0; nq < 4; ++nq)
#pragma unroll
            for (int rg = 0; rg < 4; ++rg) {
                int m = bm * 128 + wv * 32 + mq * 16 + kg * 4 + rg;
                int ncol = bn * 64 + nq * 16 + r15;
                po[(size_t)m * 256 + ncol] = acc[mq][nq][rg];
            }
}

// ---------------------------------------------------------------------------
// x -> x_pad [32*3][228][228], 2-pixel zero border.
// ---------------------------------------------------------------------------
__global__ __launch_bounds__(256) void pad_x_k(const float* __restrict__ x,
                                               float* __restrict__ xp) {
    int blk = blockIdx.x;              // 32*3*57
    int r4 = blk % 57, ic = blk / 57;
    int wid = threadIdx.x >> 6, lane = threadIdx.x & 63;
    int row = r4 * 4 + wid;
    const float* __restrict__ src = x + (size_t)ic * 224 * 224 + (size_t)(row - 2) * 224;
    float* __restrict__ dst = xp + (size_t)ic * 228 * 228 + (size_t)row * 228;
    bool rok = (row >= 2) && (row < 226);
    for (int c = lane; c < 228; c += 64) {
        float v = 0.0f;
        if (rok && c >= 2 && c < 226) v = src[c - 2];
        dst[c] = v;
    }
}

// c1p plane = 116 x 120; data ow at layout col ow+4 (border cols 2,3,116,117).
__global__ __launch_bounds__(256) void zb_c1p_k(float* __restrict__ p) {
    float* base = p + (size_t)blockIdx.x * (116 * 120);
    for (int t = threadIdx.x; t < 928; t += 256) {
        int idx;
        if (t < 480) {
            int r = t / 120, c = t - r * 120;
            int row = (r < 2) ? r : r + 112;
            idx = row * 120 + c;
        } else {
            int s = t - 480;
            int r = s >> 2, c = s & 3;
            int col = (c < 2) ? (c + 2) : (c + 114);
            idx = (r + 2) * 120 + col;
        }
        base[idx] = 0.0f;
    }
}

// c2p plane = 58 x 64; data ow at layout col ow+4 (border cols 3,60).
__global__ __launch_bounds__(64) void zb_c2p_k(float* __restrict__ p) {
    float* base = p + (size_t)blockIdx.x * (58 * 64);
    for (int t = threadIdx.x; t < 240; t += 64) {
        int idx;
        if (t < 128) {
            int r = t >> 6, c = t & 63;
            idx = (r ? 57 : 0) * 64 + c;
        } else {
            int s = t - 128;
            int r = (s >> 1) + 1;
            idx = r * 64 + ((s & 1) ? 60 : 3);
        }
        base[idx] = 0.0f;
    }
}

// ---------------------------------------------------------------------------
// ROI bilinear sampling — writes PACKED hi/lo dwords (FC consumes packed).
// ---------------------------------------------------------------------------
__global__ __launch_bounds__(256) void roi_k(const float* __restrict__ feat,
                                             const float* __restrict__ roi,
                                             unsigned* __restrict__ S) {
    int b = blockIdx.x >> 5;
    int r = blockIdx.x & 31;
    const float* rr = roi + (size_t)(b * 32 + r) * 7;

    __shared__ int   offA[100], offB[100], offC[100], offD[100];
    __shared__ float wA[100], wB[100], wC[100], wD[100];

    int tid = threadIdx.x;
    if (tid < 100) {
        int i = tid / 10, j = tid % 10;
        float cx = rr[0], cy = rr[1];
        float W1 = rr[2], W2 = rr[3], H1 = rr[4], H2 = rr[5], psi = rr[6];
        float offx = ((float)j - 4.5f) / 10.0f;
        float offy = ((float)i - 4.5f) / 10.0f;
        float gx = offx * (W1 + W2) - (W1 - W2) * 0.5f;
        float gy = offy * (H1 + H2) - (H1 - H2) * 0.5f;
        float sn = sinf(psi), cs = cosf(psi);
        float xs = gx * cs + gy * sn + cx;
        float ys = -gx * sn + gy * cs + cy;

        float x0f = floorf(xs), y0f = floorf(ys);
        int x0 = (int)x0f, x1 = x0 + 1;
        int y0 = (int)y0f, y1 = y0 + 1;
        x0 = min(max(x0, 0), 55); x1 = min(max(x1, 0), 55);
        y0 = min(max(y0, 0), 55); y1 = min(max(y1, 0), 55);
        float fx0 = (float)x0, fx1 = (float)x1;
        float fy0 = (float)y0, fy1 = (float)y1;
        float step = (fx1 - fx0) * (fy1 - fy0);
        step = fminf(fmaxf(step, 0.001f), 2.0f);
        float inv = 1.0f / step;
        wA[tid] = (fx1 - xs) * (fy1 - ys) * inv;
        wB[tid] = (fx1 - xs) * (ys - fy0) * inv;
        wC[tid] = (xs - fx0) * (fy1 - ys) * inv;
        wD[tid] = (xs - fx0) * (ys - fy0) * inv;
        offA[tid] = y0 * 56 + x0;
        offB[tid] = y1 * 56 + x0;
        offC[tid] = y0 * 56 + x1;
        offD[tid] = y1 * 56 + x1;
    }
    __syncthreads();

    const float* __restrict__ fb = feat + (size_t)b * 128 * 3136;
    unsigned* __restrict__ outb = S + ((size_t)b * 128 * 32 + r) * 100;
    int c = tid / 100;
    int p = tid - c * 100;
    for (int t = tid; t < 12800; t += 256) {
        const float* f = fb + c * 3136;
        float v = wA[p] * f[offA[p]] + wB[p] * f[offB[p]] +
                  wC[p] * f[offC[p]] + wD[p] * f[offD[p]];
        outb[(size_t)c * 3200 + p] = pack_bf16pair(v);
        p += 56; c += 2;
        if (p >= 100) { p -= 100; ++c; }
    }
}

__global__ __launch_bounds__(256) void fc2_reduce_k(const float* __restrict__ part,
                                                    const float* __restrict__ bias,
                                                    float* __restrict__ out) {
    int i = blockIdx.x * 256 + threadIdx.x;   // 0..262143
    float s = bias[i & 255];
    for (int ks = 0; ks < 16; ++ks) s += part[(size_t)ks * 262144 + i];
    out[i] = s;
}

// ---------------------------------------------------------------------------
extern "C" void kernel_launch(void* const* d_in, const int* in_sizes, int n_in,
                              void* d_out, int out_size, void* d_ws, size_t ws_size,
                              hipStream_t stream) {
    const float* x   = (const float*)d_in[0];
    const float* ROI = (const float*)d_in[1];
    const float* w1  = (const float*)d_in[2];
    const float* b1  = (const float*)d_in[3];
    const float* w2  = (const float*)d_in[4];
    const float* b2  = (const float*)d_in[5];
    const float* w3  = (const float*)d_in[6];
    const float* b3  = (const float*)d_in[7];
    const float* fcw = (const float*)d_in[8];
    const float* fcb = (const float*)d_in[9];
    float* out = (float*)d_out;

    char* ws = (char*)d_ws;
    // Workspace:
    //  c1p  [0,           57,016,320)  conv1 -> (in-place pack) -> conv2
    //  c2p  [57,016,320,  87,425,024)  conv2 -> (in-place pack) -> conv3
    //  xpad [87,425,024, 107,386,880)  pad  -> conv1        (dead after conv1)
    //  wT1  [107,386,880, 107,397,120) fp32 (conv1)
    //  wT2p [107,397,120, 107,601,920) packed (conv2)
    //  wT3p [107,601,920, 107,896,832) packed (conv3)
    //  c3   [0,           51,380,224)  conv3 -> roi      (c1p dead)
    //  S    [57,016,320, 109,445,120)  roi (PACKED) -> fc  (c2p dead)
    //  wfcp [0,           13,107,200)  packed fcw          (c3 dead after roi)
    //  part [16,777,216,  33,554,432)  fc -> reduce        (inside dead c3)
    float* c1p  = (float*)(ws);
    float* c2p  = (float*)(ws + 57016320);
    float* xpad = (float*)(ws + 87425024);
    float* wT1  = (float*)(ws + 107386880);
    unsigned* wT2p = (unsigned*)(ws + 107397120);
    unsigned* wT3p = (unsigned*)(ws + 107601920);
    float* c3   = (float*)(ws);
    unsigned* S = (unsigned*)(ws + 57016320);
    unsigned* wfcp = (unsigned*)(ws);
    float* part = (float*)(ws + 16777216);

    wtr_k<32, 75, 80><<<10, 256, 0, stream>>>(w1, wT1);
    wtr_pack_k<64, 800, 800><<<200, 256, 0, stream>>>(w2, wT2p);
    wtr_pack_k<128, 576, 576><<<288, 256, 0, stream>>>(w3, wT3p);
    pad_x_k<<<32 * 3 * 57, 256, 0, stream>>>(x, xpad);
    zb_c1p_k<<<1024, 256, 0, stream>>>(c1p);
    zb_c2p_k<<<2048, 64, 0, stream>>>(c2p);

    // conv1 (fp32): 32co x 128px, 4x4 micro, 256 thr, BK=16, MINW=4
    conv_gemm_k<3, 2, 5, 5, 75, 80, 228, 228, 0, 112, 12544,
                32, 128, 4, 4, 116, 120, 2, 4, 4, 256, 16>
        <<<3136, 256, 0, stream>>>(xpad, wT1, b1, c1p);

    // conv2 (MFMA): in-place pack c1p, then 64co x 100352px, K=800
    split_pack_k<<<4096, 256, 0, stream>>>(c1p, (unsigned*)c1p, 14254080);
    conv_mfma_k<32, 2, 5, 5, 800, 116, 120, 2, 64, 56, 58, 64, 1, 4>
        <<<dim3(49, 1, 32), 256, 0, stream>>>((unsigned*)c1p, wT2p, b2, c2p);

    // conv3 (MFMA): in-place pack c2p, then 128co x 100352px, K=576
    split_pack_k<<<4096, 256, 0, stream>>>(c2p, (unsigned*)c2p, 7602176);
    conv_mfma_k<64, 1, 3, 3, 576, 58, 64, 3, 128, 56, 56, 56, 0, 0>
        <<<dim3(49, 2, 32), 256, 0, stream>>>((unsigned*)c2p, wT3p, b3, c3);

    // ROI sampling -> packed S
    roi_k<<<1024, 256, 0, stream>>>(c3, ROI, S);
    // FC (MFMA): pack fcw, split-K 16 + reduce
    split_pack_k<<<4096, 256, 0, stream>>>(fcw, wfcp, 3276800);
    fc_mfma_k<<<dim3(4, 8, 16), 256, 0, stream>>>(S, wfcp, part);
    fc2_reduce_k<<<1024, 256, 0, stream>>>(part, fcb, out);
}

// Round 11
// 371.215 us; speedup vs baseline: 1.7306x; 1.1493x over previous
//
#include <hip/hip_runtime.h>
#include <hip/hip_bf16.h>

#define LEAK 0.2f

__device__ __forceinline__ float lrelu(float a) { return a > 0.0f ? a : LEAK * a; }

typedef __attribute__((ext_vector_type(8))) short short8;
typedef __attribute__((ext_vector_type(4))) float f32x4;

// bf16 RNE rounding done manually (no dependence on __hip_bfloat16 ABI).
__device__ __forceinline__ unsigned short bf16_hi_bits(float x) {
    unsigned u = __builtin_bit_cast(unsigned, x);
    unsigned r = u + 0x7fffu + ((u >> 16) & 1u);
    return (unsigned short)(r >> 16);
}
__device__ __forceinline__ float bf16_to_f32(unsigned short h) {
    unsigned u = ((unsigned)h) << 16;
    return __builtin_bit_cast(float, u);
}
__device__ __forceinline__ unsigned pack_bf16pair(float x) {
    unsigned short h = bf16_hi_bits(x);
    float lo = x - bf16_to_f32(h);
    return (unsigned)h | ((unsigned)bf16_hi_bits(lo) << 16);
}

// v_perm_b32 pair-packers: dwords are packed {hi-bf16 in low16, lo-bf16 in high16}.
__device__ __forceinline__ unsigned pack_lo16(unsigned o, unsigned e) {
    return __builtin_amdgcn_perm(o, e, 0x05040100u);
}
__device__ __forceinline__ unsigned pack_hi16(unsigned o, unsigned e) {
    return __builtin_amdgcn_perm(o, e, 0x07060302u);
}

// ---------------------------------------------------------------------------
// Weight transpose + bf16 hi/lo pack: wTp[k][co] = pack(w[co][k]), 0 for k>=KIN.
// ---------------------------------------------------------------------------
template<int CO, int KIN, int KP>
__global__ __launch_bounds__(256) void wtr_pack_k(const float* __restrict__ w,
                                                  unsigned* __restrict__ wTp) {
    int i = blockIdx.x * 256 + threadIdx.x;
    if (i >= KP * CO) return;
    int k = i / CO, co = i % CO;
    float x = (k < KIN) ? w[(size_t)co * KIN + k] : 0.0f;
    wTp[i] = pack_bf16pair(x);
}

// ---------------------------------------------------------------------------
// Pack fp32 -> dword {bf16 hi, bf16 lo}. In-place safe (same-index RMW).
// ---------------------------------------------------------------------------
__global__ __launch_bounds__(256) void split_pack_k(const float* __restrict__ src,
                                                    unsigned* __restrict__ dst, int n) {
    for (int i = blockIdx.x * 256 + threadIdx.x; i < n; i += gridDim.x * 256) {
        dst[i] = pack_bf16pair(src[i]);
    }
}

// ---------------------------------------------------------------------------
// conv1 as bf16 hi/lo split-GEMM on MFMA. CO=32, K=75 (pad 96), stride 2.
// Block: 32co x 128px, 4 waves; wave wv owns px [wv*32, wv*32+32), all 32 co
// -> 2x2 16x16 frags, 12 MFMA/iter, 3 iters (BK=32).
// offtab clamped at k>=75 to k=74 (weights 0, data valid -> exact 0 products,
// no NaN hazard). Packed input (xpad) / packed output (c1p).
// ---------------------------------------------------------------------------
__global__ __launch_bounds__(256, 4) void conv1_mfma_k(
    const unsigned* __restrict__ src,   // packed xpad [img*3+ci][228][228]
    const unsigned* __restrict__ wp,    // packed wT1 [96][32]
    const float* __restrict__ bias,
    unsigned* __restrict__ outp)        // packed c1p [img*32+co][116][120]
{
    // dwords: AH 0(640) | AL 640 | BH 1280(2560) | BL 3840 ; total 6400 dw
    __shared__ unsigned ldsu[6400];
    __shared__ int offtab[96];
    short* const lds = (short*)ldsu;

    const int tid  = threadIdx.x;
    const int lane = tid & 63;
    const int wv   = tid >> 6;
    const int bx   = blockIdx.x;        // 98 px tiles
    const int bz   = blockIdx.y;        // 32 imgs

    if (tid < 96) {
        int k = min(tid, 74);           // clamp padded-K tail
        int ci = k / 25, r = k - ci * 25;
        int kh = r / 5, kw = r - kh * 5;
        offtab[tid] = (ci * 228 + kh) * 228 + kw;
    }
    __syncthreads();

    // B staging: row = tid&127 (px), half = tid>>7 covers k-groups {2h, 2h+1}
    const int brow = tid & 127, half = tid >> 7;
    const int bn   = bx * 128 + brow;
    const int boh  = bn / 112, bow = bn % 112;
    const unsigned* __restrict__ bsrc =
        src + ((size_t)(bz * 3) * 228 + boh * 2) * 228 + bow * 2;
    // A staging: threads 0..127: row = tid&31 (co), ks = (tid>>5)&3
    const int arow = tid & 31, ks = (tid >> 5) & 3;

    unsigned Bu[16], Au[8];
    auto gather = [&](int it) {
        const int k0 = it * 32;
#pragma unroll
        for (int c = 0; c < 2; ++c) {
            int kb = k0 + (half * 2 + c) * 8;
            int4 o0 = *(const int4*)&offtab[kb];
            int4 o1 = *(const int4*)&offtab[kb + 4];
            Bu[c * 8 + 0] = bsrc[o0.x]; Bu[c * 8 + 1] = bsrc[o0.y];
            Bu[c * 8 + 2] = bsrc[o0.z]; Bu[c * 8 + 3] = bsrc[o0.w];
            Bu[c * 8 + 4] = bsrc[o1.x]; Bu[c * 8 + 5] = bsrc[o1.y];
            Bu[c * 8 + 6] = bsrc[o1.z]; Bu[c * 8 + 7] = bsrc[o1.w];
        }
        if (tid < 128) {
            const unsigned* __restrict__ wk = wp + (size_t)(k0 + ks * 8) * 32 + arow;
#pragma unroll
            for (int j = 0; j < 8; ++j) Au[j] = wk[j * 32];
        }
    };

    f32x4 acc[2][2] = {};
    const int r15 = lane & 15, kg = lane >> 4;

    gather(0);
    for (int it = 0; it < 3; ++it) {
        {
            uint4 vh, vl;
#pragma unroll
            for (int c = 0; c < 2; ++c) {
                vh.x = pack_lo16(Bu[c*8+1], Bu[c*8+0]); vl.x = pack_hi16(Bu[c*8+1], Bu[c*8+0]);
                vh.y = pack_lo16(Bu[c*8+3], Bu[c*8+2]); vl.y = pack_hi16(Bu[c*8+3], Bu[c*8+2]);
                vh.z = pack_lo16(Bu[c*8+5], Bu[c*8+4]); vl.z = pack_hi16(Bu[c*8+5], Bu[c*8+4]);
                vh.w = pack_lo16(Bu[c*8+7], Bu[c*8+6]); vl.w = pack_hi16(Bu[c*8+7], Bu[c*8+6]);
                *(uint4*)&ldsu[1280 + brow * 20 + (half * 2 + c) * 4] = vh;
                *(uint4*)&ldsu[3840 + brow * 20 + (half * 2 + c) * 4] = vl;
            }
            if (tid < 128) {
                vh.x = pack_lo16(Au[1], Au[0]); vl.x = pack_hi16(Au[1], Au[0]);
                vh.y = pack_lo16(Au[3], Au[2]); vl.y = pack_hi16(Au[3], Au[2]);
                vh.z = pack_lo16(Au[5], Au[4]); vl.z = pack_hi16(Au[5], Au[4]);
                vh.w = pack_lo16(Au[7], Au[6]); vl.w = pack_hi16(Au[7], Au[6]);
                *(uint4*)&ldsu[arow * 20 + ks * 4]       = vh;
                *(uint4*)&ldsu[640 + arow * 20 + ks * 4] = vl;
            }
        }
        __syncthreads();
        if (it + 1 < 3) gather(it + 1);

        const short* AsH = lds;
        const short* AsL = lds + 1280;
        const short* BsH = lds + 2560;
        const short* BsL = lds + 7680;
        short8 aH[2], aL[2], bH[2], bL[2];
#pragma unroll
        for (int tq = 0; tq < 2; ++tq) {
            const int ra = (tq * 16 + r15) * 40 + kg * 8;
            aH[tq] = *(const short8*)&AsH[ra];
            aL[tq] = *(const short8*)&AsL[ra];
            const int rb = (wv * 32 + tq * 16 + r15) * 40 + kg * 8;
            bH[tq] = *(const short8*)&BsH[rb];
            bL[tq] = *(const short8*)&BsL[rb];
        }
#pragma unroll
        for (int ct = 0; ct < 2; ++ct)
#pragma unroll
            for (int pt = 0; pt < 2; ++pt) {
                acc[ct][pt] = __builtin_amdgcn_mfma_f32_16x16x32_bf16(aH[ct], bH[pt], acc[ct][pt], 0, 0, 0);
                acc[ct][pt] = __builtin_amdgcn_mfma_f32_16x16x32_bf16(aH[ct], bL[pt], acc[ct][pt], 0, 0, 0);
                acc[ct][pt] = __builtin_amdgcn_mfma_f32_16x16x32_bf16(aL[ct], bH[pt], acc[ct][pt], 0, 0, 0);
            }
        __syncthreads();
    }

    // C/D: col = lane&15 -> px, row = (lane>>4)*4+reg -> co
#pragma unroll
    for (int ct = 0; ct < 2; ++ct)
#pragma unroll
        for (int pt = 0; pt < 2; ++pt)
#pragma unroll
            for (int rg = 0; rg < 4; ++rg) {
                int co = ct * 16 + kg * 4 + rg;
                int px = bx * 128 + wv * 32 + pt * 16 + r15;
                int poh = px / 112, pw_ = px % 112;
                float v = acc[ct][pt][rg] + bias[co];
                outp[((size_t)(bz * 32 + co) * 116 + poh + 2) * 120 + pw_ + 4] =
                    pack_bf16pair(lrelu(v));
            }
}

// ---------------------------------------------------------------------------
// Conv as bf16 hi/lo split-GEMM on MFMA (conv2 and conv3) — v3 single-buffer
// (R10-verified: Occ 55%, conv2 75.8us). POUT: write packed dwords (feeds the
// next MFMA conv directly) vs fp32 (roi consumes fp32).
// ---------------------------------------------------------------------------
template<int CI, int ST, int KH, int KW, int KP,
         int PIH, int PIW, int LP,
         int CO, int OW, int OSH, int OSW, int OR0, int OC0, bool POUT>
__global__ __launch_bounds__(256, 4) void conv_mfma_k(
    const unsigned* __restrict__ src,   // packed act [img*CI+ci][PIH][PIW]
    const unsigned* __restrict__ wp,    // packed wT  [KP][CO]
    const float* __restrict__ bias,
    void* __restrict__ outv)
{
    constexpr int KT = KP / 32;
    __shared__ unsigned ldsu[5120];     // 4 arrays x 64 rows x 20 dw (single buf)
    __shared__ int offtab[KP];
    short* const lds = (short*)ldsu;

    const int tid  = threadIdx.x;
    const int lane = tid & 63;
    const int wv   = tid >> 6;          // wave 0..3
    const int bx   = blockIdx.x;        // 49 px tiles
    const int by   = blockIdx.y;        // CO/64 co tiles
    const int bz   = blockIdx.z;        // 32 imgs

    for (int k = tid; k < KP; k += 256) {
        int ci = k / (KH * KW), r = k - ci * (KH * KW);
        int kh = r / KW, kw = r - kh * KW;
        offtab[k] = (ci * PIH + kh) * PIW + kw;
    }
    __syncthreads();

    const int row = lane;               // staging row; k-slot = wave (8 k each)
    const int n   = bx * 64 + row;      // 0..3135
    const int oh  = n / OW, ow = n % OW;
    const unsigned* __restrict__ bsrc =
        src + ((size_t)(bz * CI) * PIH + oh * ST) * PIW + ow * ST + LP;
    const unsigned* __restrict__ wsrc = wp + (size_t)(wv * 8) * CO + by * 64 + row;

    unsigned Au[8], Bu[8];
    auto gather = [&](int it) {
        const int k0 = it * 32 + wv * 8;
        int4 o0 = *(const int4*)&offtab[k0];       // broadcast ds_read
        int4 o1 = *(const int4*)&offtab[k0 + 4];
        const unsigned* __restrict__ wk = wsrc + (size_t)it * 32 * CO;
#pragma unroll
        for (int j = 0; j < 8; ++j) Au[j] = wk[j * CO];
        Bu[0] = bsrc[o0.x]; Bu[1] = bsrc[o0.y]; Bu[2] = bsrc[o0.z]; Bu[3] = bsrc[o0.w];
        Bu[4] = bsrc[o1.x]; Bu[5] = bsrc[o1.y]; Bu[6] = bsrc[o1.z]; Bu[7] = bsrc[o1.w];
    };

    f32x4 acc[2][2] = {};

    const int cw = wv & 1, pw = wv >> 1;
    const int r15 = lane & 15, kg = lane >> 4;

    gather(0);
    for (int it = 0; it < KT; ++it) {
        {
            const int widx = row * 20 + wv * 4;    // dword index within array
            uint4 vh, vl;
            vh.x = pack_lo16(Au[1], Au[0]); vl.x = pack_hi16(Au[1], Au[0]);
            vh.y = pack_lo16(Au[3], Au[2]); vl.y = pack_hi16(Au[3], Au[2]);
            vh.z = pack_lo16(Au[5], Au[4]); vl.z = pack_hi16(Au[5], Au[4]);
            vh.w = pack_lo16(Au[7], Au[6]); vl.w = pack_hi16(Au[7], Au[6]);
            *(uint4*)&ldsu[0 * 1280 + widx] = vh;
            *(uint4*)&ldsu[1 * 1280 + widx] = vl;
            vh.x = pack_lo16(Bu[1], Bu[0]); vl.x = pack_hi16(Bu[1], Bu[0]);
            vh.y = pack_lo16(Bu[3], Bu[2]); vl.y = pack_hi16(Bu[3], Bu[2]);
            vh.z = pack_lo16(Bu[5], Bu[4]); vl.z = pack_hi16(Bu[5], Bu[4]);
            vh.w = pack_lo16(Bu[7], Bu[6]); vl.w = pack_hi16(Bu[7], Bu[6]);
            *(uint4*)&ldsu[2 * 1280 + widx] = vh;
            *(uint4*)&ldsu[3 * 1280 + widx] = vl;
        }
        __syncthreads();
        if (it + 1 < KT) gather(it + 1);

        const short* AsH = lds + 0 * 2560;
        const short* AsL = lds + 1 * 2560;
        const short* BsH = lds + 2 * 2560;
        const short* BsL = lds + 3 * 2560;
        short8 aH[2], aL[2], bH[2], bL[2];
#pragma unroll
        for (int tq = 0; tq < 2; ++tq) {
            const int ra = (cw * 32 + tq * 16 + r15) * 40 + kg * 8;
            aH[tq] = *(const short8*)&AsH[ra];
            aL[tq] = *(const short8*)&AsL[ra];
            const int rb = (pw * 32 + tq * 16 + r15) * 40 + kg * 8;
            bH[tq] = *(const short8*)&BsH[rb];
            bL[tq] = *(const short8*)&BsL[rb];
        }
#pragma unroll
        for (int ct = 0; ct < 2; ++ct)
#pragma unroll
            for (int pt = 0; pt < 2; ++pt) {
                acc[ct][pt] = __builtin_amdgcn_mfma_f32_16x16x32_bf16(aH[ct], bH[pt], acc[ct][pt], 0, 0, 0);
                acc[ct][pt] = __builtin_amdgcn_mfma_f32_16x16x32_bf16(aH[ct], bL[pt], acc[ct][pt], 0, 0, 0);
                acc[ct][pt] = __builtin_amdgcn_mfma_f32_16x16x32_bf16(aL[ct], bH[pt], acc[ct][pt], 0, 0, 0);
            }
        __syncthreads();
    }

    // C/D: col = lane&15 -> px, row = (lane>>4)*4+reg -> co
#pragma unroll
    for (int ct = 0; ct < 2; ++ct)
#pragma unroll
        for (int pt = 0; pt < 2; ++pt)
#pragma unroll
            for (int rg = 0; rg < 4; ++rg) {
                int co = by * 64 + cw * 32 + ct * 16 + kg * 4 + rg;
                int px = bx * 64 + pw * 32 + pt * 16 + r15;
                int poh = px / OW, pow_ = px % OW;
                float v = lrelu(acc[ct][pt][rg] + bias[co]);
                size_t off = ((size_t)(bz * CO + co) * OSH + (poh + OR0)) * OSW + (pow_ + OC0);
                if (POUT) ((unsigned*)outv)[off] = pack_bf16pair(v);
                else      ((float*)outv)[off]    = v;
            }
}

// ---------------------------------------------------------------------------
// FC as bf16 hi/lo split-GEMM on MFMA — v2 single-buffer (R10-verified).
// ---------------------------------------------------------------------------
__global__ __launch_bounds__(256, 4) void fc_mfma_k(
    const unsigned* __restrict__ Sp,   // packed [1024][12800]
    const unsigned* __restrict__ Wp,   // packed [256][12800]
    float* __restrict__ part)          // [16][1024][256]
{
    // dword offsets: AH 0 | AL 2560 | BH 5120 | BL 6400 ; total 7680 dw
    __shared__ unsigned ldsu[7680];
    short* const lds = (short*)ldsu;

    const int tid  = threadIdx.x;
    const int lane = tid & 63;
    const int wv   = tid >> 6;
    const int bn = blockIdx.x, bm = blockIdx.y, ks = blockIdx.z;

    const int ra = tid & 127, ca = tid >> 7;
    const int rb = tid & 63,  cb = tid >> 6;
    const unsigned* __restrict__ aptr = Sp + (size_t)(bm * 128 + ra) * 12800 + ks * 800;
    const unsigned* __restrict__ bptr = Wp + (size_t)(bn * 64 + rb) * 12800 + ks * 800;

    unsigned Au[16], Bu[8];
    auto gather = [&](int it) {
        const int k0 = it * 32;
#pragma unroll
        for (int j = 0; j < 8; ++j) {
            Au[j]     = aptr[k0 + ca * 8 + j];
            Au[8 + j] = aptr[k0 + (ca + 2) * 8 + j];
            Bu[j]     = bptr[k0 + cb * 8 + j];
        }
    };

    f32x4 acc[2][4] = {};
    const int r15 = lane & 15, kg = lane >> 4;

    gather(0);
    for (int it = 0; it < 25; ++it) {
        {
            uint4 vh, vl;
            vh.x = pack_lo16(Au[1], Au[0]); vl.x = pack_hi16(Au[1], Au[0]);
            vh.y = pack_lo16(Au[3], Au[2]); vl.y = pack_hi16(Au[3], Au[2]);
            vh.z = pack_lo16(Au[5], Au[4]); vl.z = pack_hi16(Au[5], Au[4]);
            vh.w = pack_lo16(Au[7], Au[6]); vl.w = pack_hi16(Au[7], Au[6]);
            *(uint4*)&ldsu[ra * 20 + ca * 4]        = vh;
            *(uint4*)&ldsu[2560 + ra * 20 + ca * 4] = vl;
            vh.x = pack_lo16(Au[9],  Au[8]);  vl.x = pack_hi16(Au[9],  Au[8]);
            vh.y = pack_lo16(Au[11], Au[10]); vl.y = pack_hi16(Au[11], Au[10]);
            vh.z = pack_lo16(Au[13], Au[12]); vl.z = pack_hi16(Au[13], Au[12]);
            vh.w = pack_lo16(Au[15], Au[14]); vl.w = pack_hi16(Au[15], Au[14]);
            *(uint4*)&ldsu[ra * 20 + (ca + 2) * 4]        = vh;
            *(uint4*)&ldsu[2560 + ra * 20 + (ca + 2) * 4] = vl;
            vh.x = pack_lo16(Bu[1], Bu[0]); vl.x = pack_hi16(Bu[1], Bu[0]);
            vh.y = pack_lo16(Bu[3], Bu[2]); vl.y = pack_hi16(Bu[3], Bu[2]);
            vh.z = pack_lo16(Bu[5], Bu[4]); vl.z = pack_hi16(Bu[5], Bu[4]);
            vh.w = pack_lo16(Bu[7], Bu[6]); vl.w = pack_hi16(Bu[7], Bu[6]);
            *(uint4*)&ldsu[5120 + rb * 20 + cb * 4] = vh;
            *(uint4*)&ldsu[6400 + rb * 20 + cb * 4] = vl;
        }
        __syncthreads();
        if (it + 1 < 25) gather(it + 1);

        const short* AsH = lds;
        const short* AsL = AsH + 5120;
        const short* BsH = AsH + 10240;
        const short* BsL = AsH + 12800;
        short8 aH[2], aL[2], bH[4], bL[4];
#pragma unroll
        for (int mq = 0; mq < 2; ++mq) {
            const int rr = (wv * 32 + mq * 16 + r15) * 40 + kg * 8;
            aH[mq] = *(const short8*)&AsH[rr];
            aL[mq] = *(const short8*)&AsL[rr];
        }
#pragma unroll
        for (int nq = 0; nq < 4; ++nq) {
            const int rr = (nq * 16 + r15) * 40 + kg * 8;
            bH[nq] = *(const short8*)&BsH[rr];
            bL[nq] = *(const short8*)&BsL[rr];
        }
#pragma unroll
        for (int mq = 0; mq < 2; ++mq)
#pragma unroll
            for (int nq = 0; nq < 4; ++nq) {
                acc[mq][nq] = __builtin_amdgcn_mfma_f32_16x16x32_bf16(aH[mq], bH[nq], acc[mq][nq], 0, 0, 0);
                acc[mq][nq] = __builtin_amdgcn_mfma_f32_16x16x32_bf16(aH[mq], bL[nq], acc[mq][nq], 0, 0, 0);
                acc[mq][nq] = __builtin_amdgcn_mfma_f32_16x16x32_bf16(aL[mq], bH[nq], acc[mq][nq], 0, 0, 0);
            }
        __syncthreads();
    }

    float* __restrict__ po = part + (size_t)ks * 262144;
#pragma unroll
    for (int mq = 0; mq < 2; ++mq)
#pragma unroll
        for (int nq = 0; nq < 4; ++nq)
#pragma unroll
            for (int rg = 0; rg < 4; ++rg) {
                int m = bm * 128 + wv * 32 + mq * 16 + kg * 4 + rg;
                int ncol = bn * 64 + nq * 16 + r15;
                po[(size_t)m * 256 + ncol] = acc[mq][nq][rg];
            }
}

// ---------------------------------------------------------------------------
// x -> packed x_pad [32*3][228][228], 2-pixel zero border (0 packs to 0x0).
// ---------------------------------------------------------------------------
__global__ __launch_bounds__(256) void pad_x_k(const float* __restrict__ x,
                                               unsigned* __restrict__ xp) {
    int blk = blockIdx.x;              // 32*3*57
    int r4 = blk % 57, ic = blk / 57;
    int wid = threadIdx.x >> 6, lane = threadIdx.x & 63;
    int row = r4 * 4 + wid;
    const float* __restrict__ src = x + (size_t)ic * 224 * 224 + (size_t)(row - 2) * 224;
    unsigned* __restrict__ dst = xp + (size_t)ic * 228 * 228 + (size_t)row * 228;
    bool rok = (row >= 2) && (row < 226);
    for (int c = lane; c < 228; c += 64) {
        float v = 0.0f;
        if (rok && c >= 2 && c < 226) v = src[c - 2];
        dst[c] = pack_bf16pair(v);
    }
}

// c1p plane = 116 x 120; border zeros (packed 0 == bits 0).
__global__ __launch_bounds__(256) void zb_c1p_k(float* __restrict__ p) {
    float* base = p + (size_t)blockIdx.x * (116 * 120);
    for (int t = threadIdx.x; t < 928; t += 256) {
        int idx;
        if (t < 480) {
            int r = t / 120, c = t - r * 120;
            int row = (r < 2) ? r : r + 112;
            idx = row * 120 + c;
        } else {
            int s = t - 480;
            int r = s >> 2, c = s & 3;
            int col = (c < 2) ? (c + 2) : (c + 114);
            idx = (r + 2) * 120 + col;
        }
        base[idx] = 0.0f;
    }
}

// c2p plane = 58 x 64; border zeros.
__global__ __launch_bounds__(64) void zb_c2p_k(float* __restrict__ p) {
    float* base = p + (size_t)blockIdx.x * (58 * 64);
    for (int t = threadIdx.x; t < 240; t += 64) {
        int idx;
        if (t < 128) {
            int r = t >> 6, c = t & 63;
            idx = (r ? 57 : 0) * 64 + c;
        } else {
            int s = t - 128;
            int r = (s >> 1) + 1;
            idx = r * 64 + ((s & 1) ? 60 : 3);
        }
        base[idx] = 0.0f;
    }
}

// ---------------------------------------------------------------------------
// ROI bilinear sampling — writes PACKED hi/lo dwords (FC consumes packed).
// ---------------------------------------------------------------------------
__global__ __launch_bounds__(256) void roi_k(const float* __restrict__ feat,
                                             const float* __restrict__ roi,
                                             unsigned* __restrict__ S) {
    int b = blockIdx.x >> 5;
    int r = blockIdx.x & 31;
    const float* rr = roi + (size_t)(b * 32 + r) * 7;

    __shared__ int   offA[100], offB[100], offC[100], offD[100];
    __shared__ float wA[100], wB[100], wC[100], wD[100];

    int tid = threadIdx.x;
    if (tid < 100) {
        int i = tid / 10, j = tid % 10;
        float cx = rr[0], cy = rr[1];
        float W1 = rr[2], W2 = rr[3], H1 = rr[4], H2 = rr[5], psi = rr[6];
        float offx = ((float)j - 4.5f) / 10.0f;
        float offy = ((float)i - 4.5f) / 10.0f;
        float gx = offx * (W1 + W2) - (W1 - W2) * 0.5f;
        float gy = offy * (H1 + H2) - (H1 - H2) * 0.5f;
        float sn = sinf(psi), cs = cosf(psi);
        float xs = gx * cs + gy * sn + cx;
        float ys = -gx * sn + gy * cs + cy;

        float x0f = floorf(xs), y0f = floorf(ys);
        int x0 = (int)x0f, x1 = x0 + 1;
        int y0 = (int)y0f, y1 = y0 + 1;
        x0 = min(max(x0, 0), 55); x1 = min(max(x1, 0), 55);
        y0 = min(max(y0, 0), 55); y1 = min(max(y1, 0), 55);
        float fx0 = (float)x0, fx1 = (float)x1;
        float fy0 = (float)y0, fy1 = (float)y1;
        float step = (fx1 - fx0) * (fy1 - fy0);
        step = fminf(fmaxf(step, 0.001f), 2.0f);
        float inv = 1.0f / step;
        wA[tid] = (fx1 - xs) * (fy1 - ys) * inv;
        wB[tid] = (fx1 - xs) * (ys - fy0) * inv;
        wC[tid] = (xs - fx0) * (fy1 - ys) * inv;
        wD[tid] = (xs - fx0) * (ys - fy0) * inv;
        offA[tid] = y0 * 56 + x0;
        offB[tid] = y1 * 56 + x0;
        offC[tid] = y0 * 56 + x1;
        offD[tid] = y1 * 56 + x1;
    }
    __syncthreads();

    const float* __restrict__ fb = feat + (size_t)b * 128 * 3136;
    unsigned* __restrict__ outb = S + ((size_t)b * 128 * 32 + r) * 100;
    int c = tid / 100;
    int p = tid - c * 100;
    for (int t = tid; t < 12800; t += 256) {
        const float* f = fb + c * 3136;
        float v = wA[p] * f[offA[p]] + wB[p] * f[offB[p]] +
                  wC[p] * f[offC[p]] + wD[p] * f[offD[p]];
        outb[(size_t)c * 3200 + p] = pack_bf16pair(v);
        p += 56; c += 2;
        if (p >= 100) { p -= 100; ++c; }
    }
}

__global__ __launch_bounds__(256) void fc2_reduce_k(const float* __restrict__ part,
                                                    const float* __restrict__ bias,
                                                    float* __restrict__ out) {
    int i = blockIdx.x * 256 + threadIdx.x;   // 0..262143
    float s = bias[i & 255];
    for (int ks = 0; ks < 16; ++ks) s += part[(size_t)ks * 262144 + i];
    out[i] = s;
}

// ---------------------------------------------------------------------------
extern "C" void kernel_launch(void* const* d_in, const int* in_sizes, int n_in,
                              void* d_out, int out_size, void* d_ws, size_t ws_size,
                              hipStream_t stream) {
    const float* x   = (const float*)d_in[0];
    const float* ROI = (const float*)d_in[1];
    const float* w1  = (const float*)d_in[2];
    const float* b1  = (const float*)d_in[3];
    const float* w2  = (const float*)d_in[4];
    const float* b2  = (const float*)d_in[5];
    const float* w3  = (const float*)d_in[6];
    const float* b3  = (const float*)d_in[7];
    const float* fcw = (const float*)d_in[8];
    const float* fcb = (const float*)d_in[9];
    float* out = (float*)d_out;

    char* ws = (char*)d_ws;
    // Workspace:
    //  c1p  [0,           57,016,320)  conv1 (packed) -> conv2
    //  c2p  [57,016,320,  87,425,024)  conv2 (packed) -> conv3
    //  xpad [87,425,024, 107,386,880)  pad (packed) -> conv1  (dead after conv1)
    //  wT1p [107,386,880, 107,399,168) packed (conv1, 96x32)
    //  wT2p [107,399,168, 107,603,968) packed (conv2)
    //  wT3p [107,603,968, 107,898,880) packed (conv3)
    //  c3   [0,           51,380,224)  conv3 (fp32) -> roi   (c1p dead)
    //  S    [57,016,320, 109,445,120)  roi (PACKED) -> fc    (c2p dead)
    //  wfcp [0,           13,107,200)  packed fcw            (c3 dead after roi)
    //  part [16,777,216,  33,554,432)  fc -> reduce          (inside dead c3)
    unsigned* c1p  = (unsigned*)(ws);
    unsigned* c2p  = (unsigned*)(ws + 57016320);
    unsigned* xpad = (unsigned*)(ws + 87425024);
    unsigned* wT1p = (unsigned*)(ws + 107386880);
    unsigned* wT2p = (unsigned*)(ws + 107399168);
    unsigned* wT3p = (unsigned*)(ws + 107603968);
    float* c3   = (float*)(ws);
    unsigned* S = (unsigned*)(ws + 57016320);
    unsigned* wfcp = (unsigned*)(ws);
    float* part = (float*)(ws + 16777216);

    wtr_pack_k<32, 75, 96><<<12, 256, 0, stream>>>(w1, wT1p);
    wtr_pack_k<64, 800, 800><<<200, 256, 0, stream>>>(w2, wT2p);
    wtr_pack_k<128, 576, 576><<<288, 256, 0, stream>>>(w3, wT3p);
    pad_x_k<<<32 * 3 * 57, 256, 0, stream>>>(x, xpad);
    zb_c1p_k<<<1024, 256, 0, stream>>>((float*)c1p);
    zb_c2p_k<<<2048, 64, 0, stream>>>((float*)c2p);

    // conv1 (MFMA): packed xpad -> packed c1p. 32co x 128px, KP=96.
    conv1_mfma_k<<<dim3(98, 32), 256, 0, stream>>>(xpad, wT1p, b1, c1p);

    // conv2 (MFMA): packed c1p -> packed c2p. 64co x 64px, K=800.
    conv_mfma_k<32, 2, 5, 5, 800, 116, 120, 2, 64, 56, 58, 64, 1, 4, true>
        <<<dim3(49, 1, 32), 256, 0, stream>>>(c1p, wT2p, b2, c2p);

    // conv3 (MFMA): packed c2p -> fp32 c3. 128co x 64px, K=576.
    conv_mfma_k<64, 1, 3, 3, 576, 58, 64, 3, 128, 56, 56, 56, 0, 0, false>
        <<<dim3(49, 2, 32), 256, 0, stream>>>(c2p, wT3p, b3, c3);

    // ROI sampling -> packed S
    roi_k<<<1024, 256, 0, stream>>>(c3, ROI, S);
    // FC (MFMA): pack fcw, split-K 16 + reduce
    split_pack_k<<<4096, 256, 0, stream>>>(fcw, wfcp, 3276800);
    fc_mfma_k<<<dim3(4, 8, 16), 256, 0, stream>>>(S, wfcp, part);
    fc2_reduce_k<<<1024, 256, 0, stream>>>(part, fcb, out);
}